// Round 3
// baseline (10330.250 us; speedup 1.0000x reference)
//
#include <hip/hip_runtime.h>
#include <stdint.h>
#include <math.h>

// ============================================================================
// MCFNet on MI355X (gfx950).  INPUTS FLOAT32; OUTPUT FLOAT32.
// Numerics: all tensors stored f32.  Every matmul runs on MFMA bf16 with
// 3-plane splits (x = h + m + l, rep error ~2^-27) and 6 passes
// (hh, hm, mh, hl, lh, mm).  Weights pre-split into 3 transposed bf16 planes.
//
// R3: every GEMM input is pre-split ONCE into 3 bf16 planes (split_k /
// gather_split_k / gate_split_k / SiLU-GEMM tout=3 epilogue), aliased into
// the K/V plane buffers (live ranges verified in the host schedule comments).
// gemm_ps_k: no LDS, no barriers, no split3 — direct per-wave global loads
// of pre-split planes + MFMA, 128x96 tile, grid 512 = 2 blocks/CU.
// attn_fast_k: 8-deep register ring prefetch for K and V tiles + q prefetch
// + bijective XCD-chunked block swizzle (same-b blocks share one XCD's L2).
// Slow fallback path = exact R0 (guaranteed ws fit).  Bit-identical numerics.
// ============================================================================

typedef unsigned short USH;
typedef __attribute__((ext_vector_type(8))) short short8;
typedef __attribute__((ext_vector_type(4))) float floatx4;

#define MFMA16(a, b, c) __builtin_amdgcn_mfma_f32_16x16x32_bf16((a), (b), (c), 0, 0, 0)

static constexpr int NB = 32;          // batch
static constexpr int SS = 512;         // seq len
static constexpr int DD = 768;         // model dim
static constexpr int MM = NB * SS;     // 16384 rows

__device__ __forceinline__ float bf2f(USH h) {
    return __uint_as_float(((unsigned)h) << 16);
}
__device__ __forceinline__ USH f2bf(float x) {          // round-to-nearest-even
    unsigned u = __float_as_uint(x);
    return (USH)((u + 0x7fffu + ((u >> 16) & 1u)) >> 16);
}
// 3-plane split: x = h + m + l + err, |err| <= 2^-27 |x| (residuals exact).
__device__ __forceinline__ void split3(float x, USH &h, USH &m, USH &l) {
    h = f2bf(x);
    const float r1 = x - bf2f(h);
    m = f2bf(r1);
    const float r2 = r1 - bf2f(m);
    l = f2bf(r2);
}
__device__ __forceinline__ void split3x8(const float* v, short8 &H, short8 &M, short8 &L) {
#pragma unroll
    for (int j = 0; j < 8; ++j) {
        USH h, m, l;
        split3(v[j], h, m, l);
        H[j] = (short)h; M[j] = (short)m; L[j] = (short)l;
    }
}
__device__ __forceinline__ uint2 pk4(USH a, USH b, USH c, USH d) {
    uint2 r;
    r.x = (unsigned)a | ((unsigned)b << 16);
    r.y = (unsigned)c | ((unsigned)d << 16);
    return r;
}

// ---------------------------------------------------------------------------
// Weight transpose+split: f32 [R][768] -> 3 bf16 planes [768][R].
// ---------------------------------------------------------------------------
struct TransArgs {
    const float* in[13];
    USH* o0[13]; USH* o1[13]; USH* o2[13];
    int R[13];
};

__global__ __launch_bounds__(256) void trans_k(TransArgs a) {
    const int mi = blockIdx.z;
    const float* __restrict__ in = a.in[mi];
    USH* __restrict__ o0 = a.o0[mi];
    USH* __restrict__ o1 = a.o1[mi];
    USH* __restrict__ o2 = a.o2[mi];
    const int R = a.R[mi];
    const int bx = blockIdx.x, by = blockIdx.y;
    if (bx * 32 >= R) return;
    __shared__ float t[32][33];
    const int tx = threadIdx.x & 31, ty = threadIdx.x >> 5;   // 32 x 8
#pragma unroll
    for (int i = 0; i < 4; ++i)
        t[ty + i * 8][tx] = in[(size_t)(bx * 32 + ty + i * 8) * 768 + by * 32 + tx];
    __syncthreads();
#pragma unroll
    for (int i = 0; i < 4; ++i) {
        USH h, m, l;
        split3(t[tx][ty + i * 8], h, m, l);
        const size_t o = (size_t)(by * 32 + ty + i * 8) * R + bx * 32 + tx;
        o0[o] = h; o1[o] = m; o2[o] = l;
    }
}

// ---------------------------------------------------------------------------
// Plain split: f32 X[n] -> 3 bf16 planes (row-major, same indexing).
// 8 elems / thread.  grid = Mc*3/8 blocks of 256.
// ---------------------------------------------------------------------------
__global__ __launch_bounds__(256) void split_k(const float* __restrict__ X,
        USH* __restrict__ P0, USH* __restrict__ P1, USH* __restrict__ P2) {
    const size_t g = (size_t)blockIdx.x * 256 + threadIdx.x;
    float v[8];
    *(float4*)&v[0] = ((const float4*)X)[2 * g];
    *(float4*)&v[4] = ((const float4*)X)[2 * g + 1];
    short8 H8, M8, L8;
    split3x8(v, H8, M8, L8);
    ((short8*)P0)[g] = H8;
    ((short8*)P1)[g] = M8;
    ((short8*)P2)[g] = L8;
}

// ---------------------------------------------------------------------------
// Embedding gather + split: planes[m,:] = split3(table[ids[m],:]).
// 8 elems / thread.  grid = Mc*3/8.
// ---------------------------------------------------------------------------
__global__ __launch_bounds__(256) void gather_split_k(const int* __restrict__ ids,
        const float* __restrict__ table,
        USH* __restrict__ P0, USH* __restrict__ P1, USH* __restrict__ P2) {
    const int g = blockIdx.x * 256 + threadIdx.x;
    const int m = g / 96;
    const int e = (g - m * 96) * 8;
    const int id = ids[m];
    float v[8];
    *(float4*)&v[0] = *(const float4*)(table + (size_t)id * DD + e);
    *(float4*)&v[4] = *(const float4*)(table + (size_t)id * DD + e + 4);
    short8 H8, M8, L8;
    split3x8(v, H8, M8, L8);
    const size_t o = (size_t)m * DD + e;
    *(short8*)&P0[o] = H8;
    *(short8*)&P1[o] = M8;
    *(short8*)&P2[o] = L8;
}

// ---------------------------------------------------------------------------
// Embedding gather (f32, slow path only).
// ---------------------------------------------------------------------------
__global__ __launch_bounds__(256) void gather_k(const int* __restrict__ ids,
                                                const float* __restrict__ table,
                                                float* __restrict__ dst) {
    const int g  = blockIdx.x * 256 + threadIdx.x;
    const int m  = g / 192;
    const int c4 = (g - m * 192) * 4;
    const int id = ids[m];
    *(float4*)(dst + (size_t)m * DD + c4) =
        *(const float4*)(table + (size_t)id * DD + c4);
}

// ---------------------------------------------------------------------------
// FAST GEMM: C[Mc,768] = A[Mc,K] @ W[K,768] + bias, A PRE-SPLIT 3 bf16 planes
// (A0* for k<768, A1* for k>=768 in the K=1536 concat case; row stride 768).
// W pre-split 3 planes [768][K] (ldb).  6 MFMA passes, per-element chain
// order identical to R0 (hh,hm,mh,hl,lh,mm).
// NO LDS, NO BARRIERS: direct per-wave global loads (L2-resident planes).
// Tile 128x96: 4 waves 2x2, wave = 64x48 (4x3 MFMA tiles).  grid (Mc/128, 8).
// act: 0 none, 1 SiLU.  tout: 0 f32 C row-major; 1 transposed bf16 planes
// (V^T, S*[col*Mc+row]); 3 row-major bf16 planes (S*[row*768+col]).
// ---------------------------------------------------------------------------
__global__ __launch_bounds__(256) void gemm_ps_k(
    const USH* __restrict__ AH0, const USH* __restrict__ AM0, const USH* __restrict__ AL0,
    const USH* __restrict__ AH1, const USH* __restrict__ AM1, const USH* __restrict__ AL1,
    const USH* __restrict__ B0, const USH* __restrict__ B1, const USH* __restrict__ B2,
    int ldb, const float* __restrict__ bias,
    float* __restrict__ C, USH* __restrict__ S0p, USH* __restrict__ S1p,
    USH* __restrict__ S2p, int K, int act, int tout, int Mc)
{
    const int tid  = threadIdx.x;
    const int lane = tid & 63;
    const int w    = tid >> 6;
    const int quad = lane >> 4, l15 = lane & 15;
    const int wm = (w >> 1) * 64, wn = (w & 1) * 48;
    const int gm0 = blockIdx.x * 128, gn0 = blockIdx.y * 96;

    const floatx4 zero = {0.f, 0.f, 0.f, 0.f};
    floatx4 acc[4][3];
#pragma unroll
    for (int i = 0; i < 4; ++i)
#pragma unroll
        for (int j = 0; j < 3; ++j) acc[i][j] = zero;

    const size_t abase = (size_t)(gm0 + wm + l15) * 768 + quad * 8;
    const size_t bbase = (size_t)(gn0 + wn + l15) * ldb + quad * 8;

#pragma unroll 2
    for (int k0 = 0; k0 < K; k0 += 32) {
        const USH* __restrict__ AH = (k0 < 768) ? AH0 : AH1;
        const USH* __restrict__ AM = (k0 < 768) ? AM0 : AM1;
        const USH* __restrict__ AL = (k0 < 768) ? AL0 : AL1;
        const int kof = (k0 < 768) ? k0 : (k0 - 768);

        short8 a0[4], a1f[4], a2[4];
#pragma unroll
        for (int t = 0; t < 4; ++t) {
            const size_t ao = abase + (size_t)t * (16 * 768) + kof;
            a0[t]  = *(const short8*)&AH[ao];
            a1f[t] = *(const short8*)&AM[ao];
            a2[t]  = *(const short8*)&AL[ao];
        }
#pragma unroll
        for (int j = 0; j < 3; ++j) {
            const size_t bo = bbase + (size_t)j * 16 * ldb + k0;
            const short8 b0  = *(const short8*)&B0[bo];
            const short8 b1f = *(const short8*)&B1[bo];
            const short8 b2  = *(const short8*)&B2[bo];
#pragma unroll
            for (int i = 0; i < 4; ++i) {
                acc[i][j] = MFMA16(a0[i],  b0,  acc[i][j]);
                acc[i][j] = MFMA16(a0[i],  b1f, acc[i][j]);
                acc[i][j] = MFMA16(a1f[i], b0,  acc[i][j]);
                acc[i][j] = MFMA16(a0[i],  b2,  acc[i][j]);
                acc[i][j] = MFMA16(a2[i],  b0,  acc[i][j]);
                acc[i][j] = MFMA16(a1f[i], b1f, acc[i][j]);
            }
        }
    }

    // ---- epilogue: bias (+SiLU, numpy op order) -> store ----
#pragma unroll
    for (int j = 0; j < 3; ++j) {
        const int col = gn0 + wn + j * 16 + l15;
        const float bv = bias[col];
#pragma unroll
        for (int i = 0; i < 4; ++i) {
#pragma unroll
            for (int r = 0; r < 4; ++r) {
                const int row = gm0 + wm + i * 16 + quad * 4 + r;
                float x = acc[i][j][r] + bv;
                if (act == 1) {
                    const float s = 1.0f / (1.0f + expf(-x));   // sigmoid then mul
                    x = x * s;
                }
                if (tout == 1) {
                    USH hh, mm2, ll;
                    split3(x, hh, mm2, ll);
                    const size_t o = (size_t)col * Mc + row;
                    S0p[o] = hh; S1p[o] = mm2; S2p[o] = ll;
                } else if (tout == 3) {
                    USH hh, mm2, ll;
                    split3(x, hh, mm2, ll);
                    const size_t o = (size_t)row * 768 + col;
                    S0p[o] = hh; S1p[o] = mm2; S2p[o] = ll;
                } else {
                    C[(size_t)row * 768 + col] = x;
                }
            }
        }
    }
}

// ---------------------------------------------------------------------------
// SLOW GEMM (R0, fallback path): A f32, split3 in-kernel, LDS staged.
// tout: 0 f32 row-major; 2 transposed f32 (V^T).
// ---------------------------------------------------------------------------
__global__ __launch_bounds__(256) void gemm_k(
    const float* __restrict__ A0, const float* __restrict__ A1,
    const USH* __restrict__ B0, const USH* __restrict__ B1, const USH* __restrict__ B2,
    int ldb, const float* __restrict__ bias,
    float* __restrict__ C, int K, int act, int tout, int Mc)
{
    __shared__ __align__(16) USH sA0[4096], sA1[4096], sA2[4096];
    __shared__ __align__(16) USH sB0[4096], sB1[4096], sB2[4096];

    const int tid  = threadIdx.x;
    const int lane = tid & 63;
    const int w    = tid >> 6;
    const int quad = lane >> 4, l15 = lane & 15;
    const int wm = (w >> 1) * 64, wn = (w & 1) * 64;
    const int gm0 = blockIdx.x * 128, gn0 = blockIdx.y * 128;

    const int i0 = tid * 2, i1 = tid * 2 + 1;
    const int r0 = i0 >> 2, c0 = (i0 & 3) << 3;
    const int r1 = i1 >> 2, c1 = (i1 & 3) << 3;

    const floatx4 zero = {0.f, 0.f, 0.f, 0.f};
    floatx4 acc[4][4];
#pragma unroll
    for (int i = 0; i < 4; ++i)
#pragma unroll
        for (int j = 0; j < 4; ++j) acc[i][j] = zero;

    for (int k0 = 0; k0 < K; k0 += 32) {
        const float* __restrict__ A = (k0 < 768) ? A0 : A1;
        const int kof = (k0 < 768) ? k0 : (k0 - 768);

        *(uint4*)&sB0[r0 * 32 + c0] = *(const uint4*)(B0 + (size_t)(gn0 + r0) * ldb + k0 + c0);
        *(uint4*)&sB0[r1 * 32 + c1] = *(const uint4*)(B0 + (size_t)(gn0 + r1) * ldb + k0 + c1);
        *(uint4*)&sB1[r0 * 32 + c0] = *(const uint4*)(B1 + (size_t)(gn0 + r0) * ldb + k0 + c0);
        *(uint4*)&sB1[r1 * 32 + c1] = *(const uint4*)(B1 + (size_t)(gn0 + r1) * ldb + k0 + c1);
        *(uint4*)&sB2[r0 * 32 + c0] = *(const uint4*)(B2 + (size_t)(gn0 + r0) * ldb + k0 + c0);
        *(uint4*)&sB2[r1 * 32 + c1] = *(const uint4*)(B2 + (size_t)(gn0 + r1) * ldb + k0 + c1);

#pragma unroll
        for (int u = 0; u < 4; ++u) {
            const int idx = tid + u * 256;
            const int r = idx >> 3, c = (idx & 7) * 4;
            const float4 v = *(const float4*)(A + (size_t)(gm0 + r) * 768 + kof + c);
            USH h[4], m[4], l[4];
            split3(v.x, h[0], m[0], l[0]);
            split3(v.y, h[1], m[1], l[1]);
            split3(v.z, h[2], m[2], l[2]);
            split3(v.w, h[3], m[3], l[3]);
            *(uint2*)&sA0[r * 32 + c] = pk4(h[0], h[1], h[2], h[3]);
            *(uint2*)&sA1[r * 32 + c] = pk4(m[0], m[1], m[2], m[3]);
            *(uint2*)&sA2[r * 32 + c] = pk4(l[0], l[1], l[2], l[3]);
        }
        __syncthreads();

        short8 a0[4], a1f[4], a2[4], b0[4], b1f[4], b2[4];
#pragma unroll
        for (int t = 0; t < 4; ++t) {
            const int ao = (wm + t * 16 + l15) * 32 + quad * 8;
            const int bo = (wn + t * 16 + l15) * 32 + quad * 8;
            a0[t]  = *(const short8*)&sA0[ao];
            a1f[t] = *(const short8*)&sA1[ao];
            a2[t]  = *(const short8*)&sA2[ao];
            b0[t]  = *(const short8*)&sB0[bo];
            b1f[t] = *(const short8*)&sB1[bo];
            b2[t]  = *(const short8*)&sB2[bo];
        }
#pragma unroll
        for (int i = 0; i < 4; ++i)
#pragma unroll
            for (int j = 0; j < 4; ++j) acc[i][j] = MFMA16(a0[i],  b0[j],  acc[i][j]);
#pragma unroll
        for (int i = 0; i < 4; ++i)
#pragma unroll
            for (int j = 0; j < 4; ++j) acc[i][j] = MFMA16(a0[i],  b1f[j], acc[i][j]);
#pragma unroll
        for (int i = 0; i < 4; ++i)
#pragma unroll
            for (int j = 0; j < 4; ++j) acc[i][j] = MFMA16(a1f[i], b0[j],  acc[i][j]);
#pragma unroll
        for (int i = 0; i < 4; ++i)
#pragma unroll
            for (int j = 0; j < 4; ++j) acc[i][j] = MFMA16(a0[i],  b2[j],  acc[i][j]);
#pragma unroll
        for (int i = 0; i < 4; ++i)
#pragma unroll
            for (int j = 0; j < 4; ++j) acc[i][j] = MFMA16(a2[i],  b0[j],  acc[i][j]);
#pragma unroll
        for (int i = 0; i < 4; ++i)
#pragma unroll
            for (int j = 0; j < 4; ++j) acc[i][j] = MFMA16(a1f[i], b1f[j], acc[i][j]);
        __syncthreads();
    }

#pragma unroll
    for (int j = 0; j < 4; ++j) {
        const int col = gn0 + wn + j * 16 + l15;
        const float bv = bias[col];
#pragma unroll
        for (int i = 0; i < 4; ++i) {
#pragma unroll
            for (int r = 0; r < 4; ++r) {
                const int row = gm0 + wm + i * 16 + quad * 4 + r;
                float x = acc[i][j][r] + bv;
                if (act == 1) {
                    const float s = 1.0f / (1.0f + expf(-x));
                    x = x * s;
                }
                const size_t o = (tout == 2) ? ((size_t)col * Mc + row)
                                             : ((size_t)row * 768 + col);
                C[o] = x;
            }
        }
    }
}

// ---------------------------------------------------------------------------
// RoPE cos/sin table: tab[s][i] = {cos,sin}(s * theta_i), 512 x 384.
// Bit-identical math to rope_k's per-thread computation.
// ---------------------------------------------------------------------------
__global__ __launch_bounds__(256) void tab_k(float* __restrict__ tab) {
    const int p = blockIdx.x * 256 + threadIdx.x;
    const int s = p / 384;
    const int i = p - s * 384;
    const float ef = (-2.0f * (float)i) / 768.0f;
    const float th = (float)pow(10000.0, (double)ef);
    const float ang = (float)s * th;
    float sn, cs;
    sincosf(ang, &sn, &cs);
    tab[2 * p]     = cs;
    tab[2 * p + 1] = sn;
}

__global__ __launch_bounds__(256) void rope_k(float* __restrict__ X) {
    const int p = blockIdx.x * 256 + threadIdx.x;
    const int m = p / 384;
    const int i = p - m * 384;
    const int s = m & (SS - 1);
    const float ef = (-2.0f * (float)i) / 768.0f;
    const float th = (float)pow(10000.0, (double)ef);
    const float ang = (float)s * th;
    float sn, cs;
    sincosf(ang, &sn, &cs);
    float2 x = *(float2*)(X + (size_t)m * DD + 2 * i);
    float2 y;
    y.x = x.x * cs - x.y * sn;
    y.y = x.y * cs + x.x * sn;
    *(float2*)(X + (size_t)m * DD + 2 * i) = y;
}

__global__ __launch_bounds__(256) void rope_tab_k(float* __restrict__ X,
                                                  const float* __restrict__ tab) {
    const int p = blockIdx.x * 256 + threadIdx.x;
    const int m = p / 384;
    const int i = p - m * 384;
    const int s = m & (SS - 1);
    const float2 t = *(const float2*)(tab + 2 * (s * 384 + i));
    float2 x = *(float2*)(X + (size_t)m * DD + 2 * i);
    float2 y;
    y.x = x.x * t.x - x.y * t.y;
    y.y = x.y * t.x + x.x * t.y;
    *(float2*)(X + (size_t)m * DD + 2 * i) = y;
}

// RoPE + 3-plane bf16 split (K): reads f32 X, writes planes [Mc][768].
__global__ __launch_bounds__(256) void rope_split_tab_k(
    const float* __restrict__ X, const float* __restrict__ tab,
    USH* __restrict__ P0, USH* __restrict__ P1, USH* __restrict__ P2)
{
    const int p = blockIdx.x * 256 + threadIdx.x;
    const int m = p / 384;
    const int i = p - m * 384;
    const int s = m & (SS - 1);
    const float2 t = *(const float2*)(tab + 2 * (s * 384 + i));
    const float2 x = *(const float2*)(X + (size_t)m * DD + 2 * i);
    float2 y;
    y.x = x.x * t.x - x.y * t.y;
    y.y = x.y * t.x + x.x * t.y;
    USH h0, m0, l0, h1, m1, l1;
    split3(y.x, h0, m0, l0);
    split3(y.y, h1, m1, l1);
    const size_t o = (size_t)m * DD + 2 * i;
    *(unsigned*)&P0[o] = (unsigned)h0 | ((unsigned)h1 << 16);
    *(unsigned*)&P1[o] = (unsigned)m0 | ((unsigned)m1 << 16);
    *(unsigned*)&P2[o] = (unsigned)l0 | ((unsigned)l1 << 16);
}

// ---------------------------------------------------------------------------
// FAST fused attention.  Q f32 (split once per block); K planes [Mc][768];
// V planes transposed [768][Mc].  8-deep register ring prefetch on K and V
// tiles, q prefetched one ks ahead.  XCD-chunked block swizzle.
// grid: (SS/16, chB*H), block 256.  O may alias Q (per-block row ownership).
// ---------------------------------------------------------------------------
__global__ __launch_bounds__(256) void attn_fast_k(
    const float* __restrict__ Q,
    const USH* __restrict__ KH, const USH* __restrict__ KM, const USH* __restrict__ KL,
    const USH* __restrict__ VH, const USH* __restrict__ VM, const USH* __restrict__ VL,
    float* __restrict__ O, int H, int hd, int Mc)
{
    __shared__ __align__(16) float S[16][520];      // scores; later P0|P1 overlay
    __shared__ __align__(16) USH P2buf[16 * 520];   // P lo plane
    __shared__ float red[16][16];
    __shared__ float stat[16];

    const int tid  = threadIdx.x;
    const int lane = tid & 63;
    const int w    = tid >> 6;
    const int quad = lane >> 4, l15 = lane & 15;

    // XCD-chunked swizzle (bijective: tot % 8 == 0): consecutive new ids
    // (same b,h working set) land on one XCD's L2.
    const int nbx = gridDim.x;                      // 32
    const int tot = nbx * gridDim.y;
    int bid = blockIdx.y * nbx + blockIdx.x;
    bid = (bid & 7) * (tot >> 3) + (bid >> 3);
    const int yy = bid / nbx;
    const int q0 = (bid - yy * nbx) * 16;
    const int b = yy / H;
    const int h = yy - b * H;

    const floatx4 zero = {0.f, 0.f, 0.f, 0.f};

    // ---- phase 1: scores.  wave w covers keys [w*128, w*128+128) ----
    floatx4 acc[8];
#pragma unroll
    for (int t = 0; t < 8; ++t) acc[t] = zero;

    const size_t qbase  = ((size_t)(b * SS + q0 + l15)) * DD + h * hd + quad * 8;
    const size_t kstrip = ((size_t)(b * SS + w * 128 + l15)) * DD + h * hd + quad * 8;
    const int nks = hd >> 5;
    const size_t TOFF = (size_t)16 * DD;

    short8 k0h,k0m,k0l, k1h,k1m,k1l, k2h,k2m,k2l, k3h,k3m,k3l,
           k4h,k4m,k4l, k5h,k5m,k5l, k6h,k6m,k6l, k7h,k7m,k7l;
#define KLD(D, OFS) { const size_t _o = (OFS); \
        k##D##h = *(const short8*)&KH[_o]; \
        k##D##m = *(const short8*)&KM[_o]; \
        k##D##l = *(const short8*)&KL[_o]; }

    KLD(0, kstrip + 0 * TOFF)
    KLD(1, kstrip + 1 * TOFF)
    KLD(2, kstrip + 2 * TOFF)
    KLD(3, kstrip + 3 * TOFF)
    KLD(4, kstrip + 4 * TOFF)
    KLD(5, kstrip + 5 * TOFF)
    KLD(6, kstrip + 6 * TOFF)
    KLD(7, kstrip + 7 * TOFF)

    float qv[8];
    *(float4*)&qv[0] = *(const float4*)(Q + qbase);
    *(float4*)&qv[4] = *(const float4*)(Q + qbase + 4);
    short8 qh, qm, ql;
    split3x8(qv, qh, qm, ql);

#define ST1(T) \
        acc[T] = MFMA16(qh, k##T##h, acc[T]); \
        acc[T] = MFMA16(qh, k##T##m, acc[T]); \
        acc[T] = MFMA16(qm, k##T##h, acc[T]); \
        acc[T] = MFMA16(qh, k##T##l, acc[T]); \
        acc[T] = MFMA16(ql, k##T##h, acc[T]); \
        acc[T] = MFMA16(qm, k##T##m, acc[T]); \
        KLD(T, knxt + T * TOFF) \
        __builtin_amdgcn_sched_barrier(0);

    for (int ks = 0; ks < nks; ++ks) {
        const int nx = (ks + 1 < nks) ? (ks + 1) : ks;   // clamped (values unused on last iter)
        const size_t knxt = kstrip + (size_t)nx * 32;
        float qn[8];
        *(float4*)&qn[0] = *(const float4*)(Q + qbase + (size_t)nx * 32);
        *(float4*)&qn[4] = *(const float4*)(Q + qbase + (size_t)nx * 32 + 4);
        ST1(0) ST1(1) ST1(2) ST1(3) ST1(4) ST1(5) ST1(6) ST1(7)
        split3x8(qn, qh, qm, ql);
    }
#undef ST1
#undef KLD

#pragma unroll
    for (int t = 0; t < 8; ++t)
#pragma unroll
        for (int r = 0; r < 4; ++r)
            S[quad * 4 + r][w * 128 + t * 16 + l15] = acc[t][r] * 8.0f;
    __syncthreads();

    // ---- phase 2: softmax (16 threads per row, 32 cols each) ----
    const int row = tid >> 4, c16 = tid & 15;
    const int cb = c16 * 32;
    float mx = -3.4e38f;
#pragma unroll 8
    for (int c = 0; c < 32; ++c) mx = fmaxf(mx, S[row][cb + c]);
    red[row][c16] = mx;
    __syncthreads();
    if (c16 == 0) {
        float m2 = red[row][0];
#pragma unroll
        for (int j = 1; j < 16; ++j) m2 = fmaxf(m2, red[row][j]);
        stat[row] = m2;
    }
    __syncthreads();
    mx = stat[row];
    float ev[32];
    float sum = 0.f;
#pragma unroll 8
    for (int c = 0; c < 32; ++c) {
        ev[c] = expf(S[row][cb + c] - mx);
        sum += ev[c];
    }
    red[row][c16] = sum;
    __syncthreads();
    if (c16 == 0) {
        float s2 = 0.f;
#pragma unroll
        for (int j = 0; j < 16; ++j) s2 += red[row][j];
        stat[row] = s2;
    }
    __syncthreads();                       // all S reads done -> overlay P
    const float den = stat[row];
    USH* const P0 = (USH*)&S[0][0];        // P hi plane
    USH* const P1 = P0 + 16 * 520;         // P mid plane
    USH* const P2 = P2buf;                 // P lo plane
#pragma unroll 8
    for (int c = 0; c < 32; ++c) {
        const float pr = ev[c] / den;      // divide, like numpy softmax
        USH hh, mm, ll;
        split3(pr, hh, mm, ll);
        P0[row * 520 + cb + c] = hh;
        P1[row * 520 + cb + c] = mm;
        P2[row * 520 + cb + c] = ll;
    }
    __syncthreads();

    // ---- phase 3: O = P V.  wave w covers n-tiles nt = w, w+4, ... ----
    const int nnt = hd >> 4;
    const int pb = l15 * 520 + quad * 8;

    short8 v0h,v0m,v0l, v1h,v1m,v1l, v2h,v2m,v2l, v3h,v3m,v3l,
           v4h,v4m,v4l, v5h,v5m,v5l, v6h,v6m,v6l, v7h,v7m,v7l;
#define VLD(D, OFS) { const size_t _o = (OFS); \
        v##D##h = *(const short8*)&VH[_o]; \
        v##D##m = *(const short8*)&VM[_o]; \
        v##D##l = *(const short8*)&VL[_o]; }
#define ST3(KS, D) { \
        const short8 ph = *(const short8*)&P0[pb + (KS) * 32]; \
        const short8 pm = *(const short8*)&P1[pb + (KS) * 32]; \
        const short8 pl = *(const short8*)&P2[pb + (KS) * 32]; \
        o = MFMA16(ph, v##D##h, o); \
        o = MFMA16(ph, v##D##m, o); \
        o = MFMA16(pm, v##D##h, o); \
        o = MFMA16(ph, v##D##l, o); \
        o = MFMA16(pl, v##D##h, o); \
        o = MFMA16(pm, v##D##m, o); \
        VLD(D, ((KS) < 8) ? (vb + ((KS) + 8) * 32) : (vb2 + ((KS) - 8) * 32)) \
        __builtin_amdgcn_sched_barrier(0); }

    {   // preload first nt's 8 V tiles
        const int colg0 = h * hd + w * 16 + l15;
        const size_t vbp = (size_t)colg0 * Mc + b * SS + quad * 8;
        VLD(0, vbp + 0 * 32)
        VLD(1, vbp + 1 * 32)
        VLD(2, vbp + 2 * 32)
        VLD(3, vbp + 3 * 32)
        VLD(4, vbp + 4 * 32)
        VLD(5, vbp + 5 * 32)
        VLD(6, vbp + 6 * 32)
        VLD(7, vbp + 7 * 32)
    }
    for (int nt = w; nt < nnt; nt += 4) {
        const int colg = h * hd + nt * 16 + l15;
        const size_t vb  = (size_t)colg * Mc + b * SS + quad * 8;
        const size_t vb2 = (nt + 4 < nnt) ? (vb + (size_t)64 * Mc) : vb;   // clamped
        floatx4 o = zero;
        ST3(0, 0)  ST3(1, 1)  ST3(2, 2)  ST3(3, 3)
        ST3(4, 4)  ST3(5, 5)  ST3(6, 6)  ST3(7, 7)
        ST3(8, 0)  ST3(9, 1)  ST3(10, 2) ST3(11, 3)
        ST3(12, 4) ST3(13, 5) ST3(14, 6) ST3(15, 7)
#pragma unroll
        for (int r = 0; r < 4; ++r) {
            const int orow = b * SS + q0 + quad * 4 + r;
            O[(size_t)orow * 768 + colg] = o[r];
        }
    }
#undef ST3
#undef VLD
}

// ---------------------------------------------------------------------------
// SLOW (R0) fused attention: Q,K f32 row-major; V f32 transposed [768][Mc].
// ---------------------------------------------------------------------------
__global__ __launch_bounds__(256) void attn_k(
    const float* __restrict__ Q, const float* __restrict__ Kp,
    const float* __restrict__ Vt, float* __restrict__ O,
    int H, int hd, int Mc)
{
    __shared__ __align__(16) float S[16][520];
    __shared__ __align__(16) USH P2buf[16 * 520];
    __shared__ float red[16][16];
    __shared__ float stat[16];

    const int tid  = threadIdx.x;
    const int lane = tid & 63;
    const int w    = tid >> 6;
    const int quad = lane >> 4, l15 = lane & 15;
    const int b = blockIdx.y / H;
    const int h = blockIdx.y - b * H;
    const int q0 = blockIdx.x * 16;

    const floatx4 zero = {0.f, 0.f, 0.f, 0.f};

    floatx4 acc[8];
#pragma unroll
    for (int t = 0; t < 8; ++t) acc[t] = zero;

    const size_t qbase = ((size_t)(b * SS + q0 + l15)) * DD + h * hd;
    const int nks = hd >> 5;
    for (int ks = 0; ks < nks; ++ks) {
        const int co = ks * 32 + quad * 8;
        float qv[8];
        *(float4*)&qv[0] = *(const float4*)(Q + qbase + co);
        *(float4*)&qv[4] = *(const float4*)(Q + qbase + co + 4);
        short8 qh, qm, ql;
        split3x8(qv, qh, qm, ql);
#pragma unroll
        for (int t = 0; t < 8; ++t) {
            const size_t kb = ((size_t)(b * SS + w * 128 + t * 16 + l15)) * DD + h * hd + co;
            float kv[8];
            *(float4*)&kv[0] = *(const float4*)(Kp + kb);
            *(float4*)&kv[4] = *(const float4*)(Kp + kb + 4);
            short8 kh, km, kl;
            split3x8(kv, kh, km, kl);
            acc[t] = MFMA16(qh, kh, acc[t]);
            acc[t] = MFMA16(qh, km, acc[t]);
            acc[t] = MFMA16(qm, kh, acc[t]);
            acc[t] = MFMA16(qh, kl, acc[t]);
            acc[t] = MFMA16(ql, kh, acc[t]);
            acc[t] = MFMA16(qm, km, acc[t]);
        }
    }
#pragma unroll
    for (int t = 0; t < 8; ++t)
#pragma unroll
        for (int r = 0; r < 4; ++r)
            S[quad * 4 + r][w * 128 + t * 16 + l15] = acc[t][r] * 8.0f;
    __syncthreads();

    const int row = tid >> 4, c16 = tid & 15;
    const int cb = c16 * 32;
    float mx = -3.4e38f;
#pragma unroll 8
    for (int c = 0; c < 32; ++c) mx = fmaxf(mx, S[row][cb + c]);
    red[row][c16] = mx;
    __syncthreads();
    if (c16 == 0) {
        float m2 = red[row][0];
#pragma unroll
        for (int j = 1; j < 16; ++j) m2 = fmaxf(m2, red[row][j]);
        stat[row] = m2;
    }
    __syncthreads();
    mx = stat[row];
    float ev[32];
    float sum = 0.f;
#pragma unroll 8
    for (int c = 0; c < 32; ++c) {
        ev[c] = expf(S[row][cb + c] - mx);
        sum += ev[c];
    }
    red[row][c16] = sum;
    __syncthreads();
    if (c16 == 0) {
        float s2 = 0.f;
#pragma unroll
        for (int j = 0; j < 16; ++j) s2 += red[row][j];
        stat[row] = s2;
    }
    __syncthreads();
    const float den = stat[row];
    USH* const P0 = (USH*)&S[0][0];
    USH* const P1 = P0 + 16 * 520;
    USH* const P2 = P2buf;
#pragma unroll 8
    for (int c = 0; c < 32; ++c) {
        const float pr = ev[c] / den;
        USH hh, mm, ll;
        split3(pr, hh, mm, ll);
        P0[row * 520 + cb + c] = hh;
        P1[row * 520 + cb + c] = mm;
        P2[row * 520 + cb + c] = ll;
    }
    __syncthreads();

    const int nnt = hd >> 4;
    for (int nt = w; nt < nnt; nt += 4) {
        floatx4 o = zero;
        const int colg = h * hd + nt * 16 + l15;
        const size_t vb = (size_t)colg * Mc + b * SS;
        for (int ks = 0; ks < 16; ++ks) {
            const int ko = ks * 32 + quad * 8;
            const short8 ph = *(const short8*)&P0[l15 * 520 + ko];
            const short8 pm = *(const short8*)&P1[l15 * 520 + ko];
            const short8 pl = *(const short8*)&P2[l15 * 520 + ko];
            float vv[8];
            *(float4*)&vv[0] = *(const float4*)(Vt + vb + ko);
            *(float4*)&vv[4] = *(const float4*)(Vt + vb + ko + 4);
            short8 vh, vm, vl;
            split3x8(vv, vh, vm, vl);
            o = MFMA16(ph, vh, o);
            o = MFMA16(ph, vm, o);
            o = MFMA16(pm, vh, o);
            o = MFMA16(ph, vl, o);
            o = MFMA16(pl, vh, o);
            o = MFMA16(pm, vm, o);
        }
#pragma unroll
        for (int r = 0; r < 4; ++r) {
            const int orow = b * SS + q0 + quad * 4 + r;
            O[(size_t)orow * 768 + colg] = o[r];
        }
    }
}

// ---------------------------------------------------------------------------
// Gate: x = x * softmax(x, row) + x, in-place f32. 1 block / row.
// gate_split_k additionally writes 3 bf16 planes (row-major) of the result.
// ---------------------------------------------------------------------------
__global__ __launch_bounds__(256) void gate_k(float* __restrict__ X) {
    __shared__ float red[256];
    const int r = blockIdx.x, tid = threadIdx.x;
    const size_t base = (size_t)r * DD;
    float x[3];
#pragma unroll
    for (int j = 0; j < 3; ++j) x[j] = X[base + tid + j * 256];
    float mx = fmaxf(x[0], fmaxf(x[1], x[2]));
    red[tid] = mx;
    __syncthreads();
    for (int s = 128; s > 0; s >>= 1) {
        if (tid < s) red[tid] = fmaxf(red[tid], red[tid + s]);
        __syncthreads();
    }
    mx = red[0];
    __syncthreads();
    float e[3];
    float sum = 0.f;
#pragma unroll
    for (int j = 0; j < 3; ++j) { e[j] = expf(x[j] - mx); sum += e[j]; }
    red[tid] = sum;
    __syncthreads();
    for (int s = 128; s > 0; s >>= 1) {
        if (tid < s) red[tid] += red[tid + s];
        __syncthreads();
    }
    const float den = red[0];
#pragma unroll
    for (int j = 0; j < 3; ++j)
        X[base + tid + j * 256] = x[j] * (e[j] / den) + x[j];
}

__global__ __launch_bounds__(256) void gate_split_k(float* __restrict__ X,
        USH* __restrict__ P0, USH* __restrict__ P1, USH* __restrict__ P2) {
    __shared__ float red[256];
    const int r = blockIdx.x, tid = threadIdx.x;
    const size_t base = (size_t)r * DD;
    float x[3];
#pragma unroll
    for (int j = 0; j < 3; ++j) x[j] = X[base + tid + j * 256];
    float mx = fmaxf(x[0], fmaxf(x[1], x[2]));
    red[tid] = mx;
    __syncthreads();
    for (int s = 128; s > 0; s >>= 1) {
        if (tid < s) red[tid] = fmaxf(red[tid], red[tid + s]);
        __syncthreads();
    }
    mx = red[0];
    __syncthreads();
    float e[3];
    float sum = 0.f;
#pragma unroll
    for (int j = 0; j < 3; ++j) { e[j] = expf(x[j] - mx); sum += e[j]; }
    red[tid] = sum;
    __syncthreads();
    for (int s = 128; s > 0; s >>= 1) {
        if (tid < s) red[tid] += red[tid + s];
        __syncthreads();
    }
    const float den = red[0];
#pragma unroll
    for (int j = 0; j < 3; ++j) {
        const int c = tid + j * 256;
        const float y = x[j] * (e[j] / den) + x[j];
        X[base + c] = y;
        USH hh, mm, ll;
        split3(y, hh, mm, ll);
        P0[base + c] = hh; P1[base + c] = mm; P2[base + c] = ll;
    }
}

// ---------------------------------------------------------------------------
// Final: es = text + F1 + F2 + F3 ;  out = es * softmax(es,row) + es  (f32)
// ---------------------------------------------------------------------------
__global__ __launch_bounds__(256) void final_k(
    const float* __restrict__ text,
    const float* __restrict__ F1, const float* __restrict__ F2,
    const float* __restrict__ F3, float* __restrict__ out)
{
    __shared__ float red[256];
    const int r = blockIdx.x, tid = threadIdx.x;
    const size_t base = (size_t)r * DD;
    float x[3];
#pragma unroll
    for (int j = 0; j < 3; ++j) {
        const int c = tid + j * 256;
        x[j] = ((text[base + c] + F1[base + c]) + F2[base + c]) + F3[base + c];
    }
    float mx = fmaxf(x[0], fmaxf(x[1], x[2]));
    red[tid] = mx;
    __syncthreads();
    for (int s = 128; s > 0; s >>= 1) {
        if (tid < s) red[tid] = fmaxf(red[tid], red[tid + s]);
        __syncthreads();
    }
    mx = red[0];
    __syncthreads();
    float e[3];
    float sum = 0.f;
#pragma unroll
    for (int j = 0; j < 3; ++j) { e[j] = expf(x[j] - mx); sum += e[j]; }
    red[tid] = sum;
    __syncthreads();
    for (int s = 128; s > 0; s >>= 1) {
        if (tid < s) red[tid] += red[tid + s];
        __syncthreads();
    }
    const float den = red[0];
#pragma unroll
    for (int j = 0; j < 3; ++j) {
        const int c = tid + j * 256;
        out[base + c] = x[j] * (e[j] / den) + x[j];
    }
}

// ===========================================================================
// Host orchestration — dual path.
// ===========================================================================
extern "C" void kernel_launch(void* const* d_in, const int* in_sizes, int n_in,
                              void* d_out, int out_size, void* d_ws, size_t ws_size,
                              hipStream_t stream)
{
    (void)in_sizes; (void)n_in; (void)out_size;

    const float* text    = (const float*)d_in[0];
    const int*   vis_ids = (const int*)d_in[1];
    const int*   ac_ids  = (const int*)d_in[2];
    const float* vis_tab = (const float*)d_in[3];
    const float* ac_tab  = (const float*)d_in[4];
    const float* hv_wq = (const float*)d_in[5],  *hv_bq = (const float*)d_in[6];
    const float* hv_wk = (const float*)d_in[7],  *hv_bk = (const float*)d_in[8];
    const float* hv_wv = (const float*)d_in[9],  *hv_bv = (const float*)d_in[10];
    const float* ha_wq = (const float*)d_in[11], *ha_bq = (const float*)d_in[12];
    const float* ha_wk = (const float*)d_in[13], *ha_bk = (const float*)d_in[14];
    const float* ha_wv = (const float*)d_in[15], *ha_bv = (const float*)d_in[16];
    const float* ht_wq = (const float*)d_in[17], *ht_bq = (const float*)d_in[18];
    const float* ht_wk = (const float*)d_in[19], *ht_bk = (const float*)d_in[20];
    const float* ht_wv = (const float*)d_in[21], *ht_bv = (const float*)d_in[22];
    const float* ht_fcw = (const float*)d_in[23], *ht_fcb = (const float*)d_in[24];
    const float* ffn_w1 = (const float*)d_in[25], *ffn_b1 = (const float*)d_in[26];
    const float* ffn_w2 = (const float*)d_in[27], *ffn_b2 = (const float*)d_in[28];
    const float* cat_w  = (const float*)d_in[29], *cat_b  = (const float*)d_in[30];

    // ---------------- workspace sizing ----------------
    // ws in [227.2MB (R2 fast fit proven), 276MB).  fast@8192 = 227.2MB.
    const size_t SQ   = (size_t)768 * 768;                     // USH per plane
    const size_t WUSH = 3 * (12 * SQ + (size_t)768 * 1536);    // 24,772,608 USH
    const size_t TABF = (size_t)512 * 384 * 2;                 // floats
    int Mc = 0, fast = 0;
    for (int cand = MM; cand >= 512; cand >>= 1) {
        const size_t nf = WUSH * sizeof(USH) + TABF * 4 + (size_t)cand * 768 * 28;
        const size_t ns = WUSH * sizeof(USH) + (size_t)cand * 768 * 24;
        if (nf <= ws_size) { Mc = cand; fast = 1; break; }
        if (ns <= ws_size) { Mc = cand; fast = 0; break; }
    }
    if (Mc == 0) return;    // diagnostic: wrong output, not a fault
    const int nchunk = MM / Mc;
    const int chB    = Mc / SS;

    USH* p = (USH*)d_ws;
    USH *wt0[13], *wt1[13], *wt2[13];
    for (int i = 0; i < 13; ++i) {
        const size_t sz = (i == 12) ? (size_t)768 * 1536 : SQ;
        wt0[i] = p; p += sz;
        wt1[i] = p; p += sz;
        wt2[i] = p; p += sz;
    }

    // weight indices: 0 hv_wq 1 hv_wk 2 hv_wv 3 ha_wq 4 ha_wk 5 ha_wv
    //                 6 ht_wq 7 ht_wk 8 ht_wv 9 ht_fcw 10 ffn_w1 11 ffn_w2 12 cat_w
    TransArgs ta;
    const float* tin[13] = {hv_wq, hv_wk, hv_wv, ha_wq, ha_wk, ha_wv,
                            ht_wq, ht_wk, ht_wv, ht_fcw, ffn_w1, ffn_w2, cat_w};
    for (int i = 0; i < 13; ++i) {
        ta.in[i] = tin[i]; ta.o0[i] = wt0[i]; ta.o1[i] = wt1[i]; ta.o2[i] = wt2[i];
        ta.R[i] = (i == 12) ? 1536 : 768;
    }
    trans_k<<<dim3(48, 24, 13), 256, 0, stream>>>(ta);

    const size_t PSZ = (size_t)Mc * 768;       // elements per plane
    const int ropeg = Mc * 384 / 256;
    const dim3 gb(256);
    const float* NULF = nullptr;
    USH* const NUSH = nullptr;

    if (fast) {
        // layout: weights | tab | A,B,C,F f32 | KH KM KL VH VM VL bf16
        // K-space (KH/KM/KL) doubles as "A planes" for GEMMs; V-space doubles
        // as cat-A1 planes and SiLU-H output planes.  Live ranges verified.
        float* tab = (float*)p;
        float* fp  = tab + TABF;
        float *A_ = fp + 0 * PSZ, *B_ = fp + 1 * PSZ;
        float *C_ = fp + 2 * PSZ, *F_ = fp + 3 * PSZ;
        USH* KH = (USH*)(fp + 4 * PSZ);
        USH* KM = KH + PSZ;  USH* KL = KM + PSZ;
        USH* VH = KL + PSZ;  USH* VM = VH + PSZ;  USH* VL = VM + PSZ;

        tab_k<<<(512 * 384) / 256, 256, 0, stream>>>(tab);

        const dim3 gg2(Mc / 128, 8);
        const int splg = Mc * 3 / 8;

#define SPL(XP)   split_k<<<splg, 256, 0, stream>>>(XP, KH, KM, KL)
#define SPLV(XP)  split_k<<<splg, 256, 0, stream>>>(XP, VH, VM, VL)
#define GTH(IDS, TB) gather_split_k<<<splg, 256, 0, stream>>>(IDS, TB, KH, KM, KL)
#define GEMMK(WI, BIAS, CP) gemm_ps_k<<<gg2, gb, 0, stream>>>(KH, KM, KL, KH, KM, KL, \
        wt0[WI], wt1[WI], wt2[WI], 768, BIAS, CP, NUSH, NUSH, NUSH, 768, 0, 0, Mc)
#define GEMMKV(WI, BIAS) gemm_ps_k<<<gg2, gb, 0, stream>>>(KH, KM, KL, KH, KM, KL, \
        wt0[WI], wt1[WI], wt2[WI], 768, BIAS, (float*)nullptr, VH, VM, VL, 768, 0, 1, Mc)
#define GEMMKH() gemm_ps_k<<<gg2, gb, 0, stream>>>(KH, KM, KL, KH, KM, KL, \
        wt0[10], wt1[10], wt2[10], 768, ffn_b1, (float*)nullptr, VH, VM, VL, 768, 1, 3, Mc)
#define GEMMVO(WI, BIAS, CP) gemm_ps_k<<<gg2, gb, 0, stream>>>(VH, VM, VL, VH, VM, VL, \
        wt0[WI], wt1[WI], wt2[WI], 768, BIAS, CP, NUSH, NUSH, NUSH, 768, 0, 0, Mc)
#define GEMMCAT(CP) gemm_ps_k<<<gg2, gb, 0, stream>>>(KH, KM, KL, VH, VM, VL, \
        wt0[12], wt1[12], wt2[12], 1536, cat_b, CP, NUSH, NUSH, NUSH, 1536, 0, 0, Mc)
#define GATES(XP) gate_split_k<<<Mc, 256, 0, stream>>>(XP, KH, KM, KL)
#define ROPE(XP)  rope_tab_k<<<ropeg, 256, 0, stream>>>(XP, tab)
#define RSPL(XP)  rope_split_tab_k<<<ropeg, 256, 0, stream>>>(XP, tab, KH, KM, KL)
#define ATTNF(QP, OP, HH, HD) \
    attn_fast_k<<<dim3(SS / 16, chB * (HH)), 256, 0, stream>>>(QP, KH, KM, KL, \
                                                  VH, VM, VL, OP, HH, HD, Mc)

        for (int c = 0; c < nchunk; ++c) {
            const float* tx = text + (size_t)c * PSZ;
            const int* vi = vis_ids + (size_t)c * Mc;
            const int* ai = ac_ids  + (size_t)c * Mc;
            float* outc = (float*)d_out + (size_t)c * PSZ;   // scratch till final

            // ---- v1 = hv(text, Ev) -> F_ ----
            SPL(tx);  GEMMK(0, hv_bq, C_);                 // Q -> C_
            GTH(vi, vis_tab);                              // Ev planes -> K-space
            GEMMK(1, hv_bk, outc);                         // K f32 -> outc
            GEMMKV(2, hv_bv);                              // V planes -> V-space
            ROPE(C_); RSPL(outc);                          // K planes -> K-space
            ATTNF(C_, F_, 1, 768);

            // ---- a1 = ha(text, Ea) -> A_ ----
            SPL(tx);  GEMMK(3, ha_bq, C_);
            GTH(ai, ac_tab);
            GEMMK(4, ha_bk, outc);  GEMMKV(5, ha_bv);
            ROPE(C_); RSPL(outc);
            ATTNF(C_, A_, 1, 768);

            // ---- v2 = hv(v1, a1) -> C_ (aliases its Q) ----
            SPL(F_);  GEMMK(0, hv_bq, C_);
            SPL(A_);  GEMMK(1, hv_bk, outc);  GEMMKV(2, hv_bv);
            ROPE(C_); RSPL(outc);
            ATTNF(C_, C_, 1, 768);

            // ---- a2 = ha(a1, v1) -> B_ (aliases its Q) ----
            SPL(A_);  GEMMK(3, ha_bq, B_);
            SPL(F_);  GEMMK(4, ha_bk, outc);  GEMMKV(5, ha_bv);
            ROPE(B_); RSPL(outc);
            ATTNF(B_, B_, 1, 768);

            // ---- F1 = ffn(gate(cat(v1,a1) @ cat_w)) -> A_ ----
            SPL(F_);                       // v1 -> K-space
            SPLV(A_);                      // a1 -> V-space
            GEMMCAT(outc);                 // T1 -> outc
            GATES(outc);                   // gate in-place + planes -> K-space
            GEMMKH();                      // H (SiLU) planes -> V-space
            GEMMVO(11, ffn_b2, A_);        // F1 -> A_

            // ---- F2 = ffn(gate(cat(v2,a2) @ cat_w)) -> C_ ----
            SPL(C_);  SPLV(B_);
            GEMMCAT(outc);
            GATES(outc);
            GEMMKH();
            GEMMVO(11, ffn_b2, C_);        // F2 -> C_

            // ---- F3 = ffn(gate(fc(ht(F1, text)))) -> F_ ----
            SPL(A_);  GEMMK(6, ht_bq, B_);                 // Q <- F1
            SPL(tx);  GEMMK(7, ht_bk, outc);  GEMMKV(8, ht_bv);
            ROPE(B_); RSPL(outc);
            ATTNF(B_, B_, 8, 96);                          // AO aliases Q
            SPL(B_);  GEMMK(9, ht_fcb, F_);                // fc -> F_
            GATES(F_);
            GEMMKH();
            GEMMVO(11, ffn_b2, F_);                        // F3 -> F_

            final_k<<<Mc, 256, 0, stream>>>(tx, A_, C_, F_, outc);
        }
#undef SPL
#undef SPLV
#undef GTH
#undef GEMMK
#undef GEMMKV
#undef GEMMKH
#undef GEMMVO
#undef GEMMCAT
#undef GATES
#undef ROPE
#undef RSPL
#undef ATTNF
    } else {
        // -------- SLOW path: exact R0 (6 f32 planes, on-the-fly splits) ------
        float* fp = (float*)p;
        float *A_ = fp + 0 * PSZ, *B_ = fp + 1 * PSZ, *C_ = fp + 2 * PSZ;
        float *D_ = fp + 3 * PSZ, *E_ = fp + 4 * PSZ, *F_ = fp + 5 * PSZ;
        const dim3 gg(Mc / 128, DD / 128);

#define GEMM(A0P, A1P, WI, LDB, BIAS, CP, KK, ACT, TOUT) \
    gemm_k<<<gg, gb, 0, stream>>>(A0P, A1P, wt0[WI], wt1[WI], wt2[WI], LDB, BIAS, \
                                  CP, KK, ACT, TOUT, Mc)
#define ROPE(XP) rope_k<<<ropeg, 256, 0, stream>>>(XP)
#define ATTN(QP, KP, VP, OP, HH, HD) \
    attn_k<<<dim3(SS / 16, chB * (HH)), 256, 0, stream>>>(QP, KP, VP, OP, HH, HD, Mc)
#define GATE(XP) gate_k<<<Mc, 256, 0, stream>>>(XP)

        for (int c = 0; c < nchunk; ++c) {
            const float* tx = text + (size_t)c * PSZ;
            const int* vi = vis_ids + (size_t)c * Mc;
            const int* ai = ac_ids  + (size_t)c * Mc;
            float* outc = (float*)d_out + (size_t)c * PSZ;

            gather_k<<<Mc * 192 / 256, 256, 0, stream>>>(vi, vis_tab, A_);
            gather_k<<<Mc * 192 / 256, 256, 0, stream>>>(ai, ac_tab, B_);

            GEMM(tx, NULF, 0, 768, hv_bq, C_, 768, 0, 0);
            GEMM(A_, NULF, 1, 768, hv_bk, D_, 768, 0, 0);
            GEMM(A_, NULF, 2, 768, hv_bv, E_, 768, 0, 2);
            ROPE(C_); ROPE(D_);
            ATTN(C_, D_, E_, F_, 1, 768);

            GEMM(tx, NULF, 3, 768, ha_bq, C_, 768, 0, 0);
            GEMM(B_, NULF, 4, 768, ha_bk, D_, 768, 0, 0);
            GEMM(B_, NULF, 5, 768, ha_bv, E_, 768, 0, 2);
            ROPE(C_); ROPE(D_);
            ATTN(C_, D_, E_, A_, 1, 768);

            GEMM(F_, NULF, 0, 768, hv_bq, C_, 768, 0, 0);
            GEMM(A_, NULF, 1, 768, hv_bk, D_, 768, 0, 0);
            GEMM(A_, NULF, 2, 768, hv_bv, E_, 768, 0, 2);
            ROPE(C_); ROPE(D_);
            ATTN(C_, D_, E_, C_, 1, 768);

            GEMM(A_, NULF, 3, 768, ha_bq, B_, 768, 0, 0);
            GEMM(F_, NULF, 4, 768, ha_bk, D_, 768, 0, 0);
            GEMM(F_, NULF, 5, 768, ha_bv, E_, 768, 0, 2);
            ROPE(B_); ROPE(D_);
            ATTN(B_, D_, E_, B_, 1, 768);

            GEMM(F_, A_, 12, 1536, cat_b, D_, 1536, 0, 0);
            GATE(D_);
            GEMM(D_, NULF, 10, 768, ffn_b1, E_, 768, 1, 0);
            GEMM(E_, NULF, 11, 768, ffn_b2, F_, 768, 0, 0);

            GEMM(C_, B_, 12, 1536, cat_b, A_, 1536, 0, 0);
            GATE(A_);
            GEMM(A_, NULF, 10, 768, ffn_b1, C_, 768, 1, 0);
            GEMM(C_, NULF, 11, 768, ffn_b2, B_, 768, 0, 0);

            GEMM(F_, NULF, 6, 768, ht_bq, C_, 768, 0, 0);
            GEMM(tx, NULF, 7, 768, ht_bk, D_, 768, 0, 0);
            GEMM(tx, NULF, 8, 768, ht_bv, E_, 768, 0, 2);
            ROPE(C_); ROPE(D_);
            ATTN(C_, D_, E_, C_, 8, 96);
            GEMM(C_, NULF, 9, 768, ht_fcb, A_, 768, 0, 0);
            GATE(A_);
            GEMM(A_, NULF, 10, 768, ffn_b1, C_, 768, 1, 0);
            GEMM(C_, NULF, 11, 768, ffn_b2, D_, 768, 0, 0);

            final_k<<<Mc, 256, 0, stream>>>(tx, F_, B_, D_, outc);
        }
#undef GEMM
#undef ROPE
#undef ATTN
#undef GATE
    }
}

// Round 4
// 7309.093 us; speedup vs baseline: 1.4133x; 1.4133x over previous
//
#include <hip/hip_runtime.h>
#include <stdint.h>
#include <math.h>

// ============================================================================
// MCFNet on MI355X (gfx950).  INPUTS FLOAT32; OUTPUT FLOAT32.
// Numerics: all tensors stored f32.  Every matmul runs on MFMA bf16 with
// 3-plane splits (x = h + m + l, rep error ~2^-27) and 6 passes
// (hh, hm, mh, hl, lh, mm).  Weights pre-split into 3 transposed bf16 planes.
//
// R4 (rebuild on the proven R2 skeleton, Mc=8192 fast layout = 227.2MB fit):
//  - attn: R2's exact kernel body + XCD-chunked bijective block swizzle only
//    (R3 proved the swizzle's L2 effect; R3's ring/sched_barrier pinning is
//    removed — it serialized the dependent MFMA chains).
//  - RoPE fused into GEMM epilogues (pair exchange via __shfl_xor(x,1);
//    cos/sin from precomputed table).  Q-GEMM -> roped f32; K-GEMM -> roped
//    3-plane bf16 row-major (no rope kernels, no K f32 bounce via d_out).
//  - V-GEMM epilogue: split3 -> LDS transpose (pad 144) -> coalesced short8
//    plane stores (was 48 scattered 2B stores/thread; prime suspect for R2's
//    GEMM anomaly).
//  - gemm_k main loop / tiling / MFMA order byte-identical to R0 (measured at
//    the ~900TF 2-barrier structural ceiling — left alone).
//  - Slow fallback path = exact R0.  Bit-identical numerics on both paths.
// ============================================================================

typedef unsigned short USH;
typedef __attribute__((ext_vector_type(8))) short short8;
typedef __attribute__((ext_vector_type(4))) float floatx4;

#define MFMA16(a, b, c) __builtin_amdgcn_mfma_f32_16x16x32_bf16((a), (b), (c), 0, 0, 0)

static constexpr int NB = 32;          // batch
static constexpr int SS = 512;         // seq len
static constexpr int DD = 768;         // model dim
static constexpr int MM = NB * SS;     // 16384 rows

__device__ __forceinline__ float bf2f(USH h) {
    return __uint_as_float(((unsigned)h) << 16);
}
__device__ __forceinline__ USH f2bf(float x) {          // round-to-nearest-even
    unsigned u = __float_as_uint(x);
    return (USH)((u + 0x7fffu + ((u >> 16) & 1u)) >> 16);
}
// 3-plane split: x = h + m + l + err, |err| <= 2^-27 |x| (residuals exact).
__device__ __forceinline__ void split3(float x, USH &h, USH &m, USH &l) {
    h = f2bf(x);
    const float r1 = x - bf2f(h);
    m = f2bf(r1);
    const float r2 = r1 - bf2f(m);
    l = f2bf(r2);
}
__device__ __forceinline__ void split3x8(const float* v, short8 &H, short8 &M, short8 &L) {
#pragma unroll
    for (int j = 0; j < 8; ++j) {
        USH h, m, l;
        split3(v[j], h, m, l);
        H[j] = (short)h; M[j] = (short)m; L[j] = (short)l;
    }
}
__device__ __forceinline__ uint2 pk4(USH a, USH b, USH c, USH d) {
    uint2 r;
    r.x = (unsigned)a | ((unsigned)b << 16);
    r.y = (unsigned)c | ((unsigned)d << 16);
    return r;
}

// ---------------------------------------------------------------------------
// Weight transpose+split: f32 [R][768] -> 3 bf16 planes [768][R].
// ---------------------------------------------------------------------------
struct TransArgs {
    const float* in[13];
    USH* o0[13]; USH* o1[13]; USH* o2[13];
    int R[13];
};

__global__ __launch_bounds__(256) void trans_k(TransArgs a) {
    const int mi = blockIdx.z;
    const float* __restrict__ in = a.in[mi];
    USH* __restrict__ o0 = a.o0[mi];
    USH* __restrict__ o1 = a.o1[mi];
    USH* __restrict__ o2 = a.o2[mi];
    const int R = a.R[mi];
    const int bx = blockIdx.x, by = blockIdx.y;
    if (bx * 32 >= R) return;
    __shared__ float t[32][33];
    const int tx = threadIdx.x & 31, ty = threadIdx.x >> 5;   // 32 x 8
#pragma unroll
    for (int i = 0; i < 4; ++i)
        t[ty + i * 8][tx] = in[(size_t)(bx * 32 + ty + i * 8) * 768 + by * 32 + tx];
    __syncthreads();
#pragma unroll
    for (int i = 0; i < 4; ++i) {
        USH h, m, l;
        split3(t[tx][ty + i * 8], h, m, l);
        const size_t o = (size_t)(by * 32 + ty + i * 8) * R + bx * 32 + tx;
        o0[o] = h; o1[o] = m; o2[o] = l;
    }
}

// ---------------------------------------------------------------------------
// Embedding gather: dst[m,:] = table[ids[m],:]  (f32 copy)
// ---------------------------------------------------------------------------
__global__ __launch_bounds__(256) void gather_k(const int* __restrict__ ids,
                                                const float* __restrict__ table,
                                                float* __restrict__ dst) {
    const int g  = blockIdx.x * 256 + threadIdx.x;
    const int m  = g / 192;
    const int c4 = (g - m * 192) * 4;
    const int id = ids[m];
    *(float4*)(dst + (size_t)m * DD + c4) =
        *(const float4*)(table + (size_t)id * DD + c4);
}

// ---------------------------------------------------------------------------
// RoPE cos/sin table: tab[s][i] = {cos,sin}(s * theta_i), 512 x 384.
// Bit-identical math to rope_k's per-thread computation.
// ---------------------------------------------------------------------------
__global__ __launch_bounds__(256) void tab_k(float* __restrict__ tab) {
    const int p = blockIdx.x * 256 + threadIdx.x;
    const int s = p / 384;
    const int i = p - s * 384;
    const float ef = (-2.0f * (float)i) / 768.0f;
    const float th = (float)pow(10000.0, (double)ef);
    const float ang = (float)s * th;
    float sn, cs;
    sincosf(ang, &sn, &cs);
    tab[2 * p]     = cs;
    tab[2 * p + 1] = sn;
}

// Slow-path RoPE (R0, pow per thread), in-place f32.
__global__ __launch_bounds__(256) void rope_k(float* __restrict__ X) {
    const int p = blockIdx.x * 256 + threadIdx.x;
    const int m = p / 384;
    const int i = p - m * 384;
    const int s = m & (SS - 1);
    const float ef = (-2.0f * (float)i) / 768.0f;
    const float th = (float)pow(10000.0, (double)ef);
    const float ang = (float)s * th;
    float sn, cs;
    sincosf(ang, &sn, &cs);
    float2 x = *(float2*)(X + (size_t)m * DD + 2 * i);
    float2 y;
    y.x = x.x * cs - x.y * sn;
    y.y = x.y * cs + x.x * sn;
    *(float2*)(X + (size_t)m * DD + 2 * i) = y;
}

// ---------------------------------------------------------------------------
// GEMM: C[Mc,768] = A[Mc,K] @ W[K,768] + bias.   A f32 (A1 = k>=768 half of
// the K=1536 concat).  W pre-split 3 bf16 planes [768][K] (ldb).  6 MFMA
// passes, in-kernel A split3 (R0 structure — measured at ceiling).
// act: 0 none, 1 SiLU.
// tout: 0 f32 row-major; 1 TRANSPOSED 3-plane bf16 (V^T) via LDS-coalesced
//       stores; 2 transposed f32 (slow path V^T); 3 row-major 3-plane bf16
//       (K planes).
// rope: 1 -> apply interleaved RoPE in epilogue (pair via __shfl_xor(x,1),
//       cos/sin from tab).  Only with act=0, tout 0 or 3.
// XCD-chunked bijective block swizzle (applies when grid %8 == 0).
// ---------------------------------------------------------------------------
__global__ __launch_bounds__(256) void gemm_k(
    const float* __restrict__ A0, const float* __restrict__ A1,
    const USH* __restrict__ B0, const USH* __restrict__ B1, const USH* __restrict__ B2,
    int ldb, const float* __restrict__ bias,
    float* __restrict__ C, USH* __restrict__ S0p, USH* __restrict__ S1p,
    USH* __restrict__ S2p, const float* __restrict__ tab,
    int K, int act, int tout, int rope, int Mc)
{
    __shared__ __align__(16) USH smem[24576];
    USH* const sA0 = smem;
    USH* const sA1 = smem + 4096;
    USH* const sA2 = smem + 8192;
    USH* const sB0 = smem + 12288;
    USH* const sB1 = smem + 16384;
    USH* const sB2 = smem + 20480;

    const int tid  = threadIdx.x;
    const int lane = tid & 63;
    const int w    = tid >> 6;
    const int quad = lane >> 4, l15 = lane & 15;
    const int wm = (w >> 1) * 64, wn = (w & 1) * 64;

    // XCD-chunked bijective swizzle: consecutive work-ids share an XCD's L2.
    const int nbx = gridDim.x;
    const int tot = nbx * (int)gridDim.y;
    int bid = blockIdx.y * nbx + blockIdx.x;
    if ((tot & 7) == 0) bid = (bid & 7) * (tot >> 3) + (bid >> 3);
    const int byy = bid / nbx;
    const int gm0 = (bid - byy * nbx) * 128, gn0 = byy * 128;

    const int i0 = tid * 2, i1 = tid * 2 + 1;
    const int r0 = i0 >> 2, c0 = (i0 & 3) << 3;
    const int r1 = i1 >> 2, c1 = (i1 & 3) << 3;

    const floatx4 zero = {0.f, 0.f, 0.f, 0.f};
    floatx4 acc[4][4];
#pragma unroll
    for (int i = 0; i < 4; ++i)
#pragma unroll
        for (int j = 0; j < 4; ++j) acc[i][j] = zero;

    for (int k0 = 0; k0 < K; k0 += 32) {
        const float* __restrict__ A = (k0 < 768) ? A0 : A1;
        const int kof = (k0 < 768) ? k0 : (k0 - 768);

        // ---- B staging: 3 pre-split planes, 2 uint4 per plane per thread ----
        *(uint4*)&sB0[r0 * 32 + c0] = *(const uint4*)(B0 + (size_t)(gn0 + r0) * ldb + k0 + c0);
        *(uint4*)&sB0[r1 * 32 + c1] = *(const uint4*)(B0 + (size_t)(gn0 + r1) * ldb + k0 + c1);
        *(uint4*)&sB1[r0 * 32 + c0] = *(const uint4*)(B1 + (size_t)(gn0 + r0) * ldb + k0 + c0);
        *(uint4*)&sB1[r1 * 32 + c1] = *(const uint4*)(B1 + (size_t)(gn0 + r1) * ldb + k0 + c1);
        *(uint4*)&sB2[r0 * 32 + c0] = *(const uint4*)(B2 + (size_t)(gn0 + r0) * ldb + k0 + c0);
        *(uint4*)&sB2[r1 * 32 + c1] = *(const uint4*)(B2 + (size_t)(gn0 + r1) * ldb + k0 + c1);

        // ---- A staging: f32 -> split3 -> 3 planes; 4 float4 per thread ----
#pragma unroll
        for (int u = 0; u < 4; ++u) {
            const int idx = tid + u * 256;           // [0,1024)
            const int r = idx >> 3, c = (idx & 7) * 4;
            const float4 v = *(const float4*)(A + (size_t)(gm0 + r) * 768 + kof + c);
            USH h[4], m[4], l[4];
            split3(v.x, h[0], m[0], l[0]);
            split3(v.y, h[1], m[1], l[1]);
            split3(v.z, h[2], m[2], l[2]);
            split3(v.w, h[3], m[3], l[3]);
            *(uint2*)&sA0[r * 32 + c] = pk4(h[0], h[1], h[2], h[3]);
            *(uint2*)&sA1[r * 32 + c] = pk4(m[0], m[1], m[2], m[3]);
            *(uint2*)&sA2[r * 32 + c] = pk4(l[0], l[1], l[2], l[3]);
        }
        __syncthreads();

        short8 a0[4], a1f[4], a2[4], b0[4], b1f[4], b2[4];
#pragma unroll
        for (int t = 0; t < 4; ++t) {
            const int ao = (wm + t * 16 + l15) * 32 + quad * 8;
            const int bo = (wn + t * 16 + l15) * 32 + quad * 8;
            a0[t]  = *(const short8*)&sA0[ao];
            a1f[t] = *(const short8*)&sA1[ao];
            a2[t]  = *(const short8*)&sA2[ao];
            b0[t]  = *(const short8*)&sB0[bo];
            b1f[t] = *(const short8*)&sB1[bo];
            b2[t]  = *(const short8*)&sB2[bo];
        }
        // 6 passes: hh, hm, mh, hl, lh, mm
#pragma unroll
        for (int i = 0; i < 4; ++i)
#pragma unroll
            for (int j = 0; j < 4; ++j) acc[i][j] = MFMA16(a0[i],  b0[j],  acc[i][j]);
#pragma unroll
        for (int i = 0; i < 4; ++i)
#pragma unroll
            for (int j = 0; j < 4; ++j) acc[i][j] = MFMA16(a0[i],  b1f[j], acc[i][j]);
#pragma unroll
        for (int i = 0; i < 4; ++i)
#pragma unroll
            for (int j = 0; j < 4; ++j) acc[i][j] = MFMA16(a1f[i], b0[j],  acc[i][j]);
#pragma unroll
        for (int i = 0; i < 4; ++i)
#pragma unroll
            for (int j = 0; j < 4; ++j) acc[i][j] = MFMA16(a0[i],  b2[j],  acc[i][j]);
#pragma unroll
        for (int i = 0; i < 4; ++i)
#pragma unroll
            for (int j = 0; j < 4; ++j) acc[i][j] = MFMA16(a2[i],  b0[j],  acc[i][j]);
#pragma unroll
        for (int i = 0; i < 4; ++i)
#pragma unroll
            for (int j = 0; j < 4; ++j) acc[i][j] = MFMA16(a1f[i], b1f[j], acc[i][j]);
        __syncthreads();
    }

    // ---- epilogue ----
    if (tout == 1) {
        // V^T planes via LDS transpose -> coalesced short8 stores.
        // sT stride 144 USH (288B: 16B-aligned rows, banks spread).
        USH* const sT = smem;                       // 128*144 = 18432 USH
#pragma unroll
        for (int p = 0; p < 3; ++p) {
            __syncthreads();
#pragma unroll
            for (int j = 0; j < 4; ++j) {
                const int col = gn0 + wn + j * 16 + l15;
                const int cl  = wn + j * 16 + l15;
                const float bv = bias ? bias[col] : 0.0f;
#pragma unroll
                for (int i = 0; i < 4; ++i) {
#pragma unroll
                    for (int r = 0; r < 4; ++r) {
                        const int rl = wm + i * 16 + quad * 4 + r;
                        USH h, m, l;
                        split3(acc[i][j][r] + bv, h, m, l);
                        sT[cl * 144 + rl] = (p == 0) ? h : ((p == 1) ? m : l);
                    }
                }
            }
            __syncthreads();
            USH* const dst = (p == 0) ? S0p : ((p == 1) ? S1p : S2p);
#pragma unroll
            for (int u = 0; u < 8; ++u) {
                const int cc = u * 256 + tid;       // [0, 2048)
                const int cl = cc >> 4, off = (cc & 15) * 8;
                *(short8*)(dst + (size_t)(gn0 + cl) * Mc + gm0 + off) =
                    *(const short8*)&sT[cl * 144 + off];
            }
        }
        return;
    }

#pragma unroll
    for (int j = 0; j < 4; ++j) {
        const int col = gn0 + wn + j * 16 + l15;
        const float bv = bias ? bias[col] : 0.0f;
#pragma unroll
        for (int i = 0; i < 4; ++i) {
#pragma unroll
            for (int r = 0; r < 4; ++r) {
                const int row = gm0 + wm + i * 16 + quad * 4 + r;
                float x = acc[i][j][r] + bv;
                if (act == 1) {
                    const float s = 1.0f / (1.0f + expf(-x));   // sigmoid then mul
                    x = x * s;
                }
                if (rope) {
                    // partner lane holds col^1, same row; same math as rope_k.
                    const float px = __shfl_xor(x, 1, 64);
                    const float2 t = *(const float2*)(tab +
                        2 * ((row & (SS - 1)) * 384 + (col >> 1)));
                    x = (col & 1) ? (x * t.x + px * t.y)
                                  : (x * t.x - px * t.y);
                }
                if (tout == 3) {
                    USH h, m, l;
                    split3(x, h, m, l);
                    const size_t o = (size_t)row * 768 + col;
                    S0p[o] = h; S1p[o] = m; S2p[o] = l;
                } else if (tout == 2) {
                    C[(size_t)col * Mc + row] = x;
                } else {
                    C[(size_t)row * 768 + col] = x;
                }
            }
        }
    }
}

// ---------------------------------------------------------------------------
// FAST fused attention (R2 body + XCD swizzle).  Q f32 (split on the fly,
// once per block), K planes [Mc][768], V planes transposed [768][Mc].
// 2-deep pipelined K loads (R2's proven form).  grid: (SS/16, chB*H), 256.
// O may alias Q (per-block row ownership).
// ---------------------------------------------------------------------------
__global__ __launch_bounds__(256) void attn_fast_k(
    const float* __restrict__ Q,
    const USH* __restrict__ KH, const USH* __restrict__ KM, const USH* __restrict__ KL,
    const USH* __restrict__ VH, const USH* __restrict__ VM, const USH* __restrict__ VL,
    float* __restrict__ O, int H, int hd, int Mc)
{
    __shared__ __align__(16) float S[16][520];      // scores; later P0|P1 overlay
    __shared__ __align__(16) USH P2buf[16 * 520];   // P lo plane
    __shared__ float red[16][16];
    __shared__ float stat[16];

    const int tid  = threadIdx.x;
    const int lane = tid & 63;
    const int w    = tid >> 6;
    const int quad = lane >> 4, l15 = lane & 15;

    // XCD-chunked bijective swizzle: same-(b,h) blocks share one XCD's L2.
    const int nbx = gridDim.x;                      // SS/16 = 32
    const int tot = nbx * (int)gridDim.y;
    int bid = blockIdx.y * nbx + blockIdx.x;
    if ((tot & 7) == 0) bid = (bid & 7) * (tot >> 3) + (bid >> 3);
    const int yy = bid / nbx;
    const int q0 = (bid - yy * nbx) * 16;
    const int b = yy / H;
    const int h = yy - b * H;

    const floatx4 zero = {0.f, 0.f, 0.f, 0.f};

    // ---- phase 1: scores.  wave w covers keys [w*128, w*128+128) ----
    floatx4 acc[8];
#pragma unroll
    for (int t = 0; t < 8; ++t) acc[t] = zero;

    const size_t qbase  = ((size_t)(b * SS + q0 + l15)) * DD + h * hd;
    const size_t kstrip = ((size_t)(b * SS + w * 128 + l15)) * DD + h * hd;
    const int nks = hd >> 5;
    for (int ks = 0; ks < nks; ++ks) {
        const int co = ks * 32 + quad * 8;
        float qv[8];
        *(float4*)&qv[0] = *(const float4*)(Q + qbase + co);
        *(float4*)&qv[4] = *(const float4*)(Q + qbase + co + 4);
        short8 qh, qm, ql;
        split3x8(qv, qh, qm, ql);

        size_t ka = kstrip + co;
        short8 khc = *(const short8*)&KH[ka];
        short8 kmc = *(const short8*)&KM[ka];
        short8 klc = *(const short8*)&KL[ka];
#pragma unroll
        for (int t = 0; t < 8; ++t) {
            short8 khn = khc, kmn = kmc, kln = klc;
            if (t < 7) {
                const size_t kb = ka + (size_t)(t + 1) * 16 * DD;
                khn = *(const short8*)&KH[kb];
                kmn = *(const short8*)&KM[kb];
                kln = *(const short8*)&KL[kb];
            }
            acc[t] = MFMA16(qh, khc, acc[t]);
            acc[t] = MFMA16(qh, kmc, acc[t]);
            acc[t] = MFMA16(qm, khc, acc[t]);
            acc[t] = MFMA16(qh, klc, acc[t]);
            acc[t] = MFMA16(ql, khc, acc[t]);
            acc[t] = MFMA16(qm, kmc, acc[t]);
            __builtin_amdgcn_sched_barrier(0);   // keep pipeline 2-deep (no hoist)
            khc = khn; kmc = kmn; klc = kln;
        }
    }
#pragma unroll
    for (int t = 0; t < 8; ++t)
#pragma unroll
        for (int r = 0; r < 4; ++r)
            S[quad * 4 + r][w * 128 + t * 16 + l15] = acc[t][r] * 8.0f;
    __syncthreads();

    // ---- phase 2: softmax (16 threads per row, 32 cols each) ----
    const int row = tid >> 4, c16 = tid & 15;
    const int cb = c16 * 32;
    float mx = -3.4e38f;
#pragma unroll 8
    for (int c = 0; c < 32; ++c) mx = fmaxf(mx, S[row][cb + c]);
    red[row][c16] = mx;
    __syncthreads();
    if (c16 == 0) {
        float m2 = red[row][0];
#pragma unroll
        for (int j = 1; j < 16; ++j) m2 = fmaxf(m2, red[row][j]);
        stat[row] = m2;
    }
    __syncthreads();
    mx = stat[row];
    float ev[32];
    float sum = 0.f;
#pragma unroll 8
    for (int c = 0; c < 32; ++c) {
        ev[c] = expf(S[row][cb + c] - mx);
        sum += ev[c];
    }
    red[row][c16] = sum;
    __syncthreads();
    if (c16 == 0) {
        float s2 = 0.f;
#pragma unroll
        for (int j = 0; j < 16; ++j) s2 += red[row][j];
        stat[row] = s2;
    }
    __syncthreads();                       // all S reads done -> overlay P
    const float den = stat[row];
    USH* const P0 = (USH*)&S[0][0];        // P hi plane
    USH* const P1 = P0 + 16 * 520;         // P mid plane
    USH* const P2 = P2buf;                 // P lo plane
#pragma unroll 8
    for (int c = 0; c < 32; ++c) {
        const float pr = ev[c] / den;      // divide, like numpy softmax
        USH hh, mm, ll;
        split3(pr, hh, mm, ll);
        P0[row * 520 + cb + c] = hh;
        P1[row * 520 + cb + c] = mm;
        P2[row * 520 + cb + c] = ll;
    }
    __syncthreads();

    // ---- phase 3: O = P V.  wave w covers n-tiles nt = w, w+4, ... ----
    const int nnt = hd >> 4;
    for (int nt = w; nt < nnt; nt += 4) {
        floatx4 o = zero;
        const int colg = h * hd + nt * 16 + l15;
        const size_t vb = (size_t)colg * Mc + b * SS;
#pragma unroll 2
        for (int ks = 0; ks < 16; ++ks) {
            const int ko = ks * 32 + quad * 8;
            const short8 ph = *(const short8*)&P0[l15 * 520 + ko];
            const short8 pm = *(const short8*)&P1[l15 * 520 + ko];
            const short8 pl = *(const short8*)&P2[l15 * 520 + ko];
            const short8 vh = *(const short8*)&VH[vb + ko];
            const short8 vm = *(const short8*)&VM[vb + ko];
            const short8 vl = *(const short8*)&VL[vb + ko];
            o = MFMA16(ph, vh, o);
            o = MFMA16(ph, vm, o);
            o = MFMA16(pm, vh, o);
            o = MFMA16(ph, vl, o);
            o = MFMA16(pl, vh, o);
            o = MFMA16(pm, vm, o);
        }
#pragma unroll
        for (int r = 0; r < 4; ++r) {
            const int orow = b * SS + q0 + quad * 4 + r;
            O[(size_t)orow * 768 + colg] = o[r];
        }
    }
}

// ---------------------------------------------------------------------------
// SLOW (R0) fused attention: Q,K f32 row-major; V f32 transposed [768][Mc].
// ---------------------------------------------------------------------------
__global__ __launch_bounds__(256) void attn_k(
    const float* __restrict__ Q, const float* __restrict__ Kp,
    const float* __restrict__ Vt, float* __restrict__ O,
    int H, int hd, int Mc)
{
    __shared__ __align__(16) float S[16][520];
    __shared__ __align__(16) USH P2buf[16 * 520];
    __shared__ float red[16][16];
    __shared__ float stat[16];

    const int tid  = threadIdx.x;
    const int lane = tid & 63;
    const int w    = tid >> 6;
    const int quad = lane >> 4, l15 = lane & 15;
    const int b = blockIdx.y / H;
    const int h = blockIdx.y - b * H;
    const int q0 = blockIdx.x * 16;

    const floatx4 zero = {0.f, 0.f, 0.f, 0.f};

    floatx4 acc[8];
#pragma unroll
    for (int t = 0; t < 8; ++t) acc[t] = zero;

    const size_t qbase = ((size_t)(b * SS + q0 + l15)) * DD + h * hd;
    const int nks = hd >> 5;
    for (int ks = 0; ks < nks; ++ks) {
        const int co = ks * 32 + quad * 8;
        float qv[8];
        *(float4*)&qv[0] = *(const float4*)(Q + qbase + co);
        *(float4*)&qv[4] = *(const float4*)(Q + qbase + co + 4);
        short8 qh, qm, ql;
        split3x8(qv, qh, qm, ql);
#pragma unroll
        for (int t = 0; t < 8; ++t) {
            const size_t kb = ((size_t)(b * SS + w * 128 + t * 16 + l15)) * DD + h * hd + co;
            float kv[8];
            *(float4*)&kv[0] = *(const float4*)(Kp + kb);
            *(float4*)&kv[4] = *(const float4*)(Kp + kb + 4);
            short8 kh, km, kl;
            split3x8(kv, kh, km, kl);
            acc[t] = MFMA16(qh, kh, acc[t]);
            acc[t] = MFMA16(qh, km, acc[t]);
            acc[t] = MFMA16(qm, kh, acc[t]);
            acc[t] = MFMA16(qh, kl, acc[t]);
            acc[t] = MFMA16(ql, kh, acc[t]);
            acc[t] = MFMA16(qm, km, acc[t]);
        }
    }
#pragma unroll
    for (int t = 0; t < 8; ++t)
#pragma unroll
        for (int r = 0; r < 4; ++r)
            S[quad * 4 + r][w * 128 + t * 16 + l15] = acc[t][r] * 8.0f;
    __syncthreads();

    const int row = tid >> 4, c16 = tid & 15;
    const int cb = c16 * 32;
    float mx = -3.4e38f;
#pragma unroll 8
    for (int c = 0; c < 32; ++c) mx = fmaxf(mx, S[row][cb + c]);
    red[row][c16] = mx;
    __syncthreads();
    if (c16 == 0) {
        float m2 = red[row][0];
#pragma unroll
        for (int j = 1; j < 16; ++j) m2 = fmaxf(m2, red[row][j]);
        stat[row] = m2;
    }
    __syncthreads();
    mx = stat[row];
    float ev[32];
    float sum = 0.f;
#pragma unroll 8
    for (int c = 0; c < 32; ++c) {
        ev[c] = expf(S[row][cb + c] - mx);
        sum += ev[c];
    }
    red[row][c16] = sum;
    __syncthreads();
    if (c16 == 0) {
        float s2 = 0.f;
#pragma unroll
        for (int j = 0; j < 16; ++j) s2 += red[row][j];
        stat[row] = s2;
    }
    __syncthreads();
    const float den = stat[row];
    USH* const P0 = (USH*)&S[0][0];
    USH* const P1 = P0 + 16 * 520;
    USH* const P2 = P2buf;
#pragma unroll 8
    for (int c = 0; c < 32; ++c) {
        const float pr = ev[c] / den;
        USH hh, mm, ll;
        split3(pr, hh, mm, ll);
        P0[row * 520 + cb + c] = hh;
        P1[row * 520 + cb + c] = mm;
        P2[row * 520 + cb + c] = ll;
    }
    __syncthreads();

    const int nnt = hd >> 4;
    for (int nt = w; nt < nnt; nt += 4) {
        floatx4 o = zero;
        const int colg = h * hd + nt * 16 + l15;
        const size_t vb = (size_t)colg * Mc + b * SS;
        for (int ks = 0; ks < 16; ++ks) {
            const int ko = ks * 32 + quad * 8;
            const short8 ph = *(const short8*)&P0[l15 * 520 + ko];
            const short8 pm = *(const short8*)&P1[l15 * 520 + ko];
            const short8 pl = *(const short8*)&P2[l15 * 520 + ko];
            float vv[8];
            *(float4*)&vv[0] = *(const float4*)(Vt + vb + ko);
            *(float4*)&vv[4] = *(const float4*)(Vt + vb + ko + 4);
            short8 vh, vm, vl;
            split3x8(vv, vh, vm, vl);
            o = MFMA16(ph, vh, o);
            o = MFMA16(ph, vm, o);
            o = MFMA16(pm, vh, o);
            o = MFMA16(ph, vl, o);
            o = MFMA16(pl, vh, o);
            o = MFMA16(pm, vm, o);
        }
#pragma unroll
        for (int r = 0; r < 4; ++r) {
            const int orow = b * SS + q0 + quad * 4 + r;
            O[(size_t)orow * 768 + colg] = o[r];
        }
    }
}

// ---------------------------------------------------------------------------
// Gate: x = x * softmax(x, row) + x, in-place f32. 1 block / row.
// ---------------------------------------------------------------------------
__global__ __launch_bounds__(256) void gate_k(float* __restrict__ X) {
    __shared__ float red[256];
    const int r = blockIdx.x, tid = threadIdx.x;
    const size_t base = (size_t)r * DD;
    float x[3];
#pragma unroll
    for (int j = 0; j < 3; ++j) x[j] = X[base + tid + j * 256];
    float mx = fmaxf(x[0], fmaxf(x[1], x[2]));
    red[tid] = mx;
    __syncthreads();
    for (int s = 128; s > 0; s >>= 1) {
        if (tid < s) red[tid] = fmaxf(red[tid], red[tid + s]);
        __syncthreads();
    }
    mx = red[0];
    __syncthreads();
    float e[3];
    float sum = 0.f;
#pragma unroll
    for (int j = 0; j < 3; ++j) { e[j] = expf(x[j] - mx); sum += e[j]; }
    red[tid] = sum;
    __syncthreads();
    for (int s = 128; s > 0; s >>= 1) {
        if (tid < s) red[tid] += red[tid + s];
        __syncthreads();
    }
    const float den = red[0];
#pragma unroll
    for (int j = 0; j < 3; ++j)
        X[base + tid + j * 256] = x[j] * (e[j] / den) + x[j];
}

// ---------------------------------------------------------------------------
// Final: es = text + F1 + F2 + F3 ;  out = es * softmax(es,row) + es  (f32)
// ---------------------------------------------------------------------------
__global__ __launch_bounds__(256) void final_k(
    const float* __restrict__ text,
    const float* __restrict__ F1, const float* __restrict__ F2,
    const float* __restrict__ F3, float* __restrict__ out)
{
    __shared__ float red[256];
    const int r = blockIdx.x, tid = threadIdx.x;
    const size_t base = (size_t)r * DD;
    float x[3];
#pragma unroll
    for (int j = 0; j < 3; ++j) {
        const int c = tid + j * 256;
        x[j] = ((text[base + c] + F1[base + c]) + F2[base + c]) + F3[base + c];
    }
    float mx = fmaxf(x[0], fmaxf(x[1], x[2]));
    red[tid] = mx;
    __syncthreads();
    for (int s = 128; s > 0; s >>= 1) {
        if (tid < s) red[tid] = fmaxf(red[tid], red[tid + s]);
        __syncthreads();
    }
    mx = red[0];
    __syncthreads();
    float e[3];
    float sum = 0.f;
#pragma unroll
    for (int j = 0; j < 3; ++j) { e[j] = expf(x[j] - mx); sum += e[j]; }
    red[tid] = sum;
    __syncthreads();
    for (int s = 128; s > 0; s >>= 1) {
        if (tid < s) red[tid] += red[tid + s];
        __syncthreads();
    }
    const float den = red[0];
#pragma unroll
    for (int j = 0; j < 3; ++j) {
        const int c = tid + j * 256;
        out[base + c] = x[j] * (e[j] / den) + x[j];
    }
}

// ===========================================================================
// Host orchestration — dual path.
// ===========================================================================
extern "C" void kernel_launch(void* const* d_in, const int* in_sizes, int n_in,
                              void* d_out, int out_size, void* d_ws, size_t ws_size,
                              hipStream_t stream)
{
    (void)in_sizes; (void)n_in; (void)out_size;

    const float* text    = (const float*)d_in[0];
    const int*   vis_ids = (const int*)d_in[1];
    const int*   ac_ids  = (const int*)d_in[2];
    const float* vis_tab = (const float*)d_in[3];
    const float* ac_tab  = (const float*)d_in[4];
    const float* hv_wq = (const float*)d_in[5],  *hv_bq = (const float*)d_in[6];
    const float* hv_wk = (const float*)d_in[7],  *hv_bk = (const float*)d_in[8];
    const float* hv_wv = (const float*)d_in[9],  *hv_bv = (const float*)d_in[10];
    const float* ha_wq = (const float*)d_in[11], *ha_bq = (const float*)d_in[12];
    const float* ha_wk = (const float*)d_in[13], *ha_bk = (const float*)d_in[14];
    const float* ha_wv = (const float*)d_in[15], *ha_bv = (const float*)d_in[16];
    const float* ht_wq = (const float*)d_in[17], *ht_bq = (const float*)d_in[18];
    const float* ht_wk = (const float*)d_in[19], *ht_bk = (const float*)d_in[20];
    const float* ht_wv = (const float*)d_in[21], *ht_bv = (const float*)d_in[22];
    const float* ht_fcw = (const float*)d_in[23], *ht_fcb = (const float*)d_in[24];
    const float* ffn_w1 = (const float*)d_in[25], *ffn_b1 = (const float*)d_in[26];
    const float* ffn_w2 = (const float*)d_in[27], *ffn_b2 = (const float*)d_in[28];
    const float* cat_w  = (const float*)d_in[29], *cat_b  = (const float*)d_in[30];

    // ---------------- workspace sizing ----------------
    // ws in [227.3MB (R2 fast fit proven), 276MB).  fast@8192 = 227.3MB.
    const size_t SQ   = (size_t)768 * 768;                     // USH per plane
    const size_t WUSH = 3 * (12 * SQ + (size_t)768 * 1536);    // 24,772,608 USH
    const size_t TABF = (size_t)512 * 384 * 2;                 // floats
    int Mc = 0, fast = 0;
    for (int cand = MM; cand >= 512; cand >>= 1) {
        const size_t nf = WUSH * sizeof(USH) + TABF * 4 + (size_t)cand * 768 * 28;
        const size_t ns = WUSH * sizeof(USH) + (size_t)cand * 768 * 24;
        if (nf <= ws_size) { Mc = cand; fast = 1; break; }
        if (ns <= ws_size) { Mc = cand; fast = 0; break; }
    }
    if (Mc == 0) return;    // diagnostic: wrong output, not a fault
    const int nchunk = MM / Mc;
    const int chB    = Mc / SS;

    USH* p = (USH*)d_ws;
    USH *wt0[13], *wt1[13], *wt2[13];
    for (int i = 0; i < 13; ++i) {
        const size_t sz = (i == 12) ? (size_t)768 * 1536 : SQ;
        wt0[i] = p; p += sz;
        wt1[i] = p; p += sz;
        wt2[i] = p; p += sz;
    }

    // weight indices: 0 hv_wq 1 hv_wk 2 hv_wv 3 ha_wq 4 ha_wk 5 ha_wv
    //                 6 ht_wq 7 ht_wk 8 ht_wv 9 ht_fcw 10 ffn_w1 11 ffn_w2 12 cat_w
    TransArgs ta;
    const float* tin[13] = {hv_wq, hv_wk, hv_wv, ha_wq, ha_wk, ha_wv,
                            ht_wq, ht_wk, ht_wv, ht_fcw, ffn_w1, ffn_w2, cat_w};
    for (int i = 0; i < 13; ++i) {
        ta.in[i] = tin[i]; ta.o0[i] = wt0[i]; ta.o1[i] = wt1[i]; ta.o2[i] = wt2[i];
        ta.R[i] = (i == 12) ? 1536 : 768;
    }
    trans_k<<<dim3(48, 24, 13), 256, 0, stream>>>(ta);

    const size_t PSZ = (size_t)Mc * 768;       // elements per plane
    const dim3 gg(Mc / 128, DD / 128), gb(256);
    const int ropeg = Mc * 384 / 256;
    const float* NULF = nullptr;
    USH* const NUSH = nullptr;

    if (fast) {
        // layout: weights | tab | A,B,C,F f32 | KH KM KL VH VM VL bf16
        float* tab = (float*)p;
        float* fp  = tab + TABF;
        float *A_ = fp + 0 * PSZ, *B_ = fp + 1 * PSZ;
        float *C_ = fp + 2 * PSZ, *F_ = fp + 3 * PSZ;
        USH* KH = (USH*)(fp + 4 * PSZ);
        USH* KM = KH + PSZ;  USH* KL = KM + PSZ;
        USH* VH = KL + PSZ;  USH* VM = VH + PSZ;  USH* VL = VM + PSZ;

        tab_k<<<(512 * 384) / 256, 256, 0, stream>>>(tab);

// plain GEMM (f32 out)
#define GE(A0P, A1P, WI, LDB, BIAS, CP, KK, ACT) \
    gemm_k<<<gg, gb, 0, stream>>>(A0P, A1P, wt0[WI], wt1[WI], wt2[WI], LDB, BIAS, \
                                  CP, NUSH, NUSH, NUSH, tab, KK, ACT, 0, 0, Mc)
// Q GEMM: rope fused, f32 out
#define GQ(A0P, WI, BIAS, CP) \
    gemm_k<<<gg, gb, 0, stream>>>(A0P, NULF, wt0[WI], wt1[WI], wt2[WI], 768, BIAS, \
                                  CP, NUSH, NUSH, NUSH, tab, 768, 0, 0, 1, Mc)
// K GEMM: rope fused, row-major 3-plane bf16 out
#define GK(A0P, WI, BIAS) \
    gemm_k<<<gg, gb, 0, stream>>>(A0P, NULF, wt0[WI], wt1[WI], wt2[WI], 768, BIAS, \
                                  (float*)nullptr, KH, KM, KL, tab, 768, 0, 3, 1, Mc)
// V GEMM: transposed 3-plane bf16 out (LDS-coalesced epilogue)
#define GV(A0P, WI, BIAS) \
    gemm_k<<<gg, gb, 0, stream>>>(A0P, NULF, wt0[WI], wt1[WI], wt2[WI], 768, BIAS, \
                                  (float*)nullptr, VH, VM, VL, tab, 768, 0, 1, 0, Mc)
#define ATTNF(QP, OP, HH, HD) \
    attn_fast_k<<<dim3(SS / 16, chB * (HH)), 256, 0, stream>>>(QP, KH, KM, KL, \
                                                  VH, VM, VL, OP, HH, HD, Mc)
#define GATE(XP) gate_k<<<Mc, 256, 0, stream>>>(XP)

        for (int c = 0; c < nchunk; ++c) {
            const float* tx = text + (size_t)c * PSZ;
            const int* vi = vis_ids + (size_t)c * Mc;
            const int* ai = ac_ids  + (size_t)c * Mc;
            float* outc = (float*)d_out + (size_t)c * PSZ;   // scratch till final

            gather_k<<<Mc * 192 / 256, 256, 0, stream>>>(vi, vis_tab, A_);  // Ev
            gather_k<<<Mc * 192 / 256, 256, 0, stream>>>(ai, ac_tab, B_);   // Ea

            // ---- v1 = hv(text, Ev) -> F_ ----
            GQ(tx, 0, hv_bq, C_);
            GK(A_, 1, hv_bk);  GV(A_, 2, hv_bv);
            ATTNF(C_, F_, 1, 768);                           // (Ev dead)

            // ---- a1 = ha(text, Ea) -> A_ ----
            GQ(tx, 3, ha_bq, C_);
            GK(B_, 4, ha_bk);  GV(B_, 5, ha_bv);
            ATTNF(C_, A_, 1, 768);                           // (Ea dead)

            // ---- v2 = hv(v1, a1) -> C_ (aliases its Q) ----
            GQ(F_, 0, hv_bq, C_);
            GK(A_, 1, hv_bk);  GV(A_, 2, hv_bv);
            ATTNF(C_, C_, 1, 768);

            // ---- a2 = ha(a1, v1) -> B_ (aliases its Q) ----
            GQ(A_, 3, ha_bq, B_);
            GK(F_, 4, ha_bk);  GV(F_, 5, ha_bv);
            ATTNF(B_, B_, 1, 768);

            // ---- F1 = ffn(gate(cat(v1,a1) @ cat_w)) -> A_ ----
            GE(F_, A_, 12, 1536, cat_b, outc, 1536, 0);      // T1
            GATE(outc);
            GE(outc, NULF, 10, 768, ffn_b1, F_, 768, 1);     // H (v1 dead)
            GE(F_, NULF, 11, 768, ffn_b2, A_, 768, 0);       // F1 -> A_ (a1 dead)

            // ---- F2 = ffn(gate(cat(v2,a2) @ cat_w)) -> C_ ----
            GE(C_, B_, 12, 1536, cat_b, outc, 1536, 0);      // T2
            GATE(outc);
            GE(outc, NULF, 10, 768, ffn_b1, F_, 768, 1);     // H
            GE(F_, NULF, 11, 768, ffn_b2, C_, 768, 0);       // F2 -> C_ (v2 dead)

            // ---- F3 = ffn(gate(fc(ht(F1, text)))) -> F_ ----
            GQ(A_, 6, ht_bq, B_);                            // Q <- F1 (a2 dead)
            GK(tx, 7, ht_bk);  GV(tx, 8, ht_bv);
            ATTNF(B_, B_, 8, 96);                            // AO aliases Q
            GE(B_, NULF, 9, 768, ht_fcb, F_, 768, 0);        // fc
            GATE(F_);
            GE(F_, NULF, 10, 768, ffn_b1, B_, 768, 1);       // H
            GE(B_, NULF, 11, 768, ffn_b2, F_, 768, 0);       // F3

            final_k<<<Mc, 256, 0, stream>>>(tx, A_, C_, F_, outc);
        }
#undef GE
#undef GQ
#undef GK
#undef GV
#undef ATTNF
#undef GATE
    } else {
        // -------- SLOW path: exact R0 (6 f32 planes, on-the-fly splits) ------
        float* fp = (float*)p;
        float *A_ = fp + 0 * PSZ, *B_ = fp + 1 * PSZ, *C_ = fp + 2 * PSZ;
        float *D_ = fp + 3 * PSZ, *E_ = fp + 4 * PSZ, *F_ = fp + 5 * PSZ;

#define GEMM(A0P, A1P, WI, LDB, BIAS, CP, KK, ACT, TOUT) \
    gemm_k<<<gg, gb, 0, stream>>>(A0P, A1P, wt0[WI], wt1[WI], wt2[WI], LDB, BIAS, \
                                  CP, NUSH, NUSH, NUSH, NULF, KK, ACT, TOUT, 0, Mc)
#define ROPE(XP) rope_k<<<ropeg, 256, 0, stream>>>(XP)
#define ATTN(QP, KP, VP, OP, HH, HD) \
    attn_k<<<dim3(SS / 16, chB * (HH)), 256, 0, stream>>>(QP, KP, VP, OP, HH, HD, Mc)
#define GATE(XP) gate_k<<<Mc, 256, 0, stream>>>(XP)

        for (int c = 0; c < nchunk; ++c) {
            const float* tx = text + (size_t)c * PSZ;
            const int* vi = vis_ids + (size_t)c * Mc;
            const int* ai = ac_ids  + (size_t)c * Mc;
            float* outc = (float*)d_out + (size_t)c * PSZ;

            gather_k<<<Mc * 192 / 256, 256, 0, stream>>>(vi, vis_tab, A_);
            gather_k<<<Mc * 192 / 256, 256, 0, stream>>>(ai, ac_tab, B_);

            GEMM(tx, NULF, 0, 768, hv_bq, C_, 768, 0, 0);
            GEMM(A_, NULF, 1, 768, hv_bk, D_, 768, 0, 0);
            GEMM(A_, NULF, 2, 768, hv_bv, E_, 768, 0, 2);
            ROPE(C_); ROPE(D_);
            ATTN(C_, D_, E_, F_, 1, 768);

            GEMM(tx, NULF, 3, 768, ha_bq, C_, 768, 0, 0);
            GEMM(B_, NULF, 4, 768, ha_bk, D_, 768, 0, 0);
            GEMM(B_, NULF, 5, 768, ha_bv, E_, 768, 0, 2);
            ROPE(C_); ROPE(D_);
            ATTN(C_, D_, E_, A_, 1, 768);

            GEMM(F_, NULF, 0, 768, hv_bq, C_, 768, 0, 0);
            GEMM(A_, NULF, 1, 768, hv_bk, D_, 768, 0, 0);
            GEMM(A_, NULF, 2, 768, hv_bv, E_, 768, 0, 2);
            ROPE(C_); ROPE(D_);
            ATTN(C_, D_, E_, C_, 1, 768);

            GEMM(A_, NULF, 3, 768, ha_bq, B_, 768, 0, 0);
            GEMM(F_, NULF, 4, 768, ha_bk, D_, 768, 0, 0);
            GEMM(F_, NULF, 5, 768, ha_bv, E_, 768, 0, 2);
            ROPE(B_); ROPE(D_);
            ATTN(B_, D_, E_, B_, 1, 768);

            GEMM(F_, A_, 12, 1536, cat_b, D_, 1536, 0, 0);
            GATE(D_);
            GEMM(D_, NULF, 10, 768, ffn_b1, E_, 768, 1, 0);
            GEMM(E_, NULF, 11, 768, ffn_b2, F_, 768, 0, 0);

            GEMM(C_, B_, 12, 1536, cat_b, A_, 1536, 0, 0);
            GATE(A_);
            GEMM(A_, NULF, 10, 768, ffn_b1, C_, 768, 1, 0);
            GEMM(C_, NULF, 11, 768, ffn_b2, B_, 768, 0, 0);

            GEMM(F_, NULF, 6, 768, ht_bq, C_, 768, 0, 0);
            GEMM(tx, NULF, 7, 768, ht_bk, D_, 768, 0, 0);
            GEMM(tx, NULF, 8, 768, ht_bv, E_, 768, 0, 2);
            ROPE(C_); ROPE(D_);
            ATTN(C_, D_, E_, C_, 8, 96);
            GEMM(C_, NULF, 9, 768, ht_fcb, A_, 768, 0, 0);
            GATE(A_);
            GEMM(A_, NULF, 10, 768, ffn_b1, C_, 768, 1, 0);
            GEMM(C_, NULF, 11, 768, ffn_b2, D_, 768, 0, 0);

            final_k<<<Mc, 256, 0, stream>>>(tx, F_, B_, D_, outc);
        }
#undef GEMM
#undef ROPE
#undef ATTN
#undef GATE
    }
}